// Round 2
// baseline (1722.160 us; speedup 1.0000x reference)
//
#include <hip/hip_runtime.h>
#include <hip/hip_bf16.h>

// GCN: 3x (h = relu( dinv .* Agg( dinv .* (h@W) ) + b)) then mean-pool by graph.
// Agg = sum over in-edges (CSR by dst) + self loop.
// Storage type T for the N x 128 ping-pong buffers is float or bf16 depending
// on ws_size; all arithmetic is fp32.

// ---------------- storage helpers ----------------

__device__ inline float ld1(const float* p, size_t i) { return p[i]; }
__device__ inline float ld1(const __hip_bfloat16* p, size_t i) { return __bfloat162float(p[i]); }
__device__ inline void st1(float* p, size_t i, float v) { p[i] = v; }
__device__ inline void st1(__hip_bfloat16* p, size_t i, float v) { p[i] = __float2bfloat16(v); }

__device__ inline float2 ld2(const float* p, size_t pair_idx) {
    return ((const float2*)p)[pair_idx];
}
__device__ inline float2 ld2(const __hip_bfloat16* p, size_t pair_idx) {
    __hip_bfloat162 v = ((const __hip_bfloat162*)p)[pair_idx];
    return make_float2(__bfloat162float(v.x), __bfloat162float(v.y));
}
__device__ inline void st2(float* p, size_t pair_idx, float2 v) {
    ((float2*)p)[pair_idx] = v;
}
__device__ inline void st2(__hip_bfloat16* p, size_t pair_idx, float2 v) {
    __hip_bfloat162 o; o.x = __float2bfloat16(v.x); o.y = __float2bfloat16(v.y);
    ((__hip_bfloat162*)p)[pair_idx] = o;
}

// ---------------- CSR build ----------------

__global__ __launch_bounds__(256) void degree_kernel(const int* __restrict__ dst,
                                                     int* __restrict__ count, int E) {
    int e = blockIdx.x * blockDim.x + threadIdx.x;
    if (e < E) atomicAdd(&count[dst[e]], 1);
}

__global__ __launch_bounds__(1024) void scan_kernel(const int* __restrict__ count,
                                                    int* __restrict__ rowptr,
                                                    int* __restrict__ cur,
                                                    float* __restrict__ dinv, int N) {
    __shared__ int ssum[1024];
    const int t = threadIdx.x;
    const int C = (N + 1023) >> 10;
    const int lo = t * C;
    const int hi = min(lo + C, N);
    int s = 0;
    for (int i = lo; i < hi; ++i) s += count[i];
    ssum[t] = s;
    __syncthreads();
    if (t == 0) {
        int run = 0;
        for (int k = 0; k < 1024; ++k) { int v = ssum[k]; ssum[k] = run; run += v; }
        rowptr[N] = run;
    }
    __syncthreads();
    int run = ssum[t];
    for (int i = lo; i < hi; ++i) {
        rowptr[i] = run;
        cur[i]    = run;
        float dg  = (float)count[i] + 1.0f;   // +1 self loop
        dinv[i]   = rsqrtf(dg);
        run += count[i];
    }
}

__global__ __launch_bounds__(256) void fill_kernel(const int* __restrict__ src,
                                                   const int* __restrict__ dst,
                                                   int* __restrict__ cur,
                                                   int* __restrict__ csr, int E) {
    int e = blockIdx.x * blockDim.x + threadIdx.x;
    if (e < E) {
        int p = atomicAdd(&cur[dst[e]], 1);
        csr[p] = src[e];
    }
}

// ---------------- matmuls (s = dinv_i * (h @ W)) ----------------

template <typename TO>
__global__ __launch_bounds__(256) void matmul1_kernel(const float* __restrict__ x,
                                                      const float* __restrict__ W,
                                                      const float* __restrict__ dinv,
                                                      TO* __restrict__ s, int N) {
    int gid = blockIdx.x * blockDim.x + threadIdx.x;
    int row = gid >> 7, col = gid & 127;
    if (row >= N) return;
    float acc = 0.f;
    const float* xr = x + (size_t)row * 26;
#pragma unroll
    for (int k = 0; k < 26; ++k) acc = fmaf(xr[k], W[k * 128 + col], acc);
    st1(s, (size_t)row * 128 + col, acc * dinv[row]);
}

template <typename TI, typename TO>
__global__ __launch_bounds__(256) void matmul128_kernel(const TI* __restrict__ h,
                                                        const float* __restrict__ W,
                                                        const float* __restrict__ dinv,
                                                        TO* __restrict__ s, int N) {
    int gid = blockIdx.x * blockDim.x + threadIdx.x;
    int row = gid >> 7, col = gid & 127;
    if (row >= N) return;
    float acc = 0.f;
    const TI* hr = h + (size_t)row * 128;
#pragma unroll 16
    for (int k = 0; k < 128; ++k) acc = fmaf(ld1(hr, k), W[k * 128 + col], acc);
    st1(s, (size_t)row * 128 + col, acc * dinv[row]);
}

// ---------------- aggregation: one wave per node ----------------

template <int RELU, typename TI, typename TO>
__global__ __launch_bounds__(256) void aggregate_kernel(const TI* __restrict__ s,
                                                        const float* __restrict__ dinv,
                                                        const int* __restrict__ rowptr,
                                                        const int* __restrict__ csr,
                                                        const float* __restrict__ bias,
                                                        TO* __restrict__ hout, int N) {
    int wid  = (int)((blockIdx.x * blockDim.x + threadIdx.x) >> 6);
    int lane = threadIdx.x & 63;
    if (wid >= N) return;
    const int i = wid;
    int start = __builtin_amdgcn_readfirstlane(rowptr[i]);
    int end   = __builtin_amdgcn_readfirstlane(rowptr[i + 1]);
    float2 acc = ld2(s, (size_t)i * 64 + lane);      // self-loop term
    for (int e = start; e < end; ++e) {
        int sn = csr[e];                              // wave-uniform -> scalar load
        float2 v = ld2(s, (size_t)sn * 64 + lane);
        acc.x += v.x; acc.y += v.y;
    }
    float di = dinv[i];
    int f = lane * 2;
    float ox = acc.x * di + bias[f];
    float oy = acc.y * di + bias[f + 1];
    if (RELU) { ox = fmaxf(ox, 0.f); oy = fmaxf(oy, 0.f); }
    st2(hout, (size_t)i * 64 + lane, make_float2(ox, oy));
}

// ---------------- mean pool ----------------

template <typename TI>
__global__ __launch_bounds__(128) void pool_kernel(const TI* __restrict__ h,
                                                   const int* __restrict__ batch,
                                                   float* __restrict__ out, int N) {
    int g = blockIdx.x;
    int j = threadIdx.x;    // 128 feature lanes
    int lo = 0, hi = N;
    while (lo < hi) { int mid = (lo + hi) >> 1; if (batch[mid] < g) lo = mid + 1; else hi = mid; }
    int start = lo;
    hi = N;
    while (lo < hi) { int mid = (lo + hi) >> 1; if (batch[mid] < g + 1) lo = mid + 1; else hi = mid; }
    int end = lo;
    float acc = 0.f;
    for (int i = start; i < end; ++i) acc += ld1(h, (size_t)i * 128 + j);
    int cnt = end - start;
    out[(size_t)g * 128 + j] = acc / (float)max(cnt, 1);
}

// ---------------- driver ----------------

template <typename T>
static void run_pipeline(const float* x, const int* src, const int* dst, const int* batch,
                         const float* W1, const float* b1, const float* W2, const float* b2,
                         const float* W3, const float* b3, float* out,
                         int N, int E, int G, char* base, hipStream_t stream) {
    // layout: [rowptr (N+1) | dinv (N) | csr (E) | bufA | bufB | count (N) | cur (N)]
    size_t off = 0;
    auto carve = [&](size_t bytes) -> char* {
        char* p = base + off;
        off = (off + bytes + 255) & ~(size_t)255;
        return p;
    };
    int*   rowptr = (int*)carve((size_t)(N + 1) * 4);
    float* dinv   = (float*)carve((size_t)N * 4);
    int*   csr    = (int*)carve((size_t)E * 4);
    T*     bufA   = (T*)carve((size_t)N * 128 * sizeof(T));
    T*     bufB   = (T*)carve((size_t)N * 128 * sizeof(T));
    // count/cur only live during CSR build, before bufA/bufB are written:
    // alias them into the bufA region to trim footprint.
    int* count = (int*)bufA;
    int* cur   = (int*)(bufA + (size_t)N * 2);  // distinct region (>=8 bytes per node in bufA half? ensure separation)
    // safer: put cur in bufB region
    cur = (int*)bufB;

    hipMemsetAsync(count, 0, (size_t)N * 4, stream);

    int ebk = (E + 255) / 256;
    degree_kernel<<<ebk, 256, 0, stream>>>(dst, count, E);
    scan_kernel<<<1, 1024, 0, stream>>>(count, rowptr, cur, dinv, N);
    fill_kernel<<<ebk, 256, 0, stream>>>(src, dst, cur, csr, E);

    int mmbk = (N * 128 + 255) / 256;
    int agbk = (N + 3) / 4;   // 4 waves per 256-thread block

    // layer 1
    matmul1_kernel<T><<<mmbk, 256, 0, stream>>>(x, W1, dinv, bufA, N);
    aggregate_kernel<1, T, T><<<agbk, 256, 0, stream>>>(bufA, dinv, rowptr, csr, b1, bufB, N);
    // layer 2
    matmul128_kernel<T, T><<<mmbk, 256, 0, stream>>>(bufB, W2, dinv, bufA, N);
    aggregate_kernel<1, T, T><<<agbk, 256, 0, stream>>>(bufA, dinv, rowptr, csr, b2, bufB, N);
    // layer 3
    matmul128_kernel<T, T><<<mmbk, 256, 0, stream>>>(bufB, W3, dinv, bufA, N);
    aggregate_kernel<0, T, T><<<agbk, 256, 0, stream>>>(bufA, dinv, rowptr, csr, b3, bufB, N);
    // pool
    pool_kernel<T><<<G, 128, 0, stream>>>(bufB, batch, out, N);
}

extern "C" void kernel_launch(void* const* d_in, const int* in_sizes, int n_in,
                              void* d_out, int out_size, void* d_ws, size_t ws_size,
                              hipStream_t stream) {
    const float* x     = (const float*)d_in[0];
    const int*   edge  = (const int*)d_in[1];
    const int*   batch = (const int*)d_in[2];
    const float* W1    = (const float*)d_in[3];
    const float* b1    = (const float*)d_in[4];
    const float* W2    = (const float*)d_in[5];
    const float* b2    = (const float*)d_in[6];
    const float* W3    = (const float*)d_in[7];
    const float* b3    = (const float*)d_in[8];
    float* out = (float*)d_out;

    const int N = in_sizes[2];
    const int E = in_sizes[1] / 2;
    const int G = out_size / 128;

    const int* src = edge;
    const int* dst = edge + E;

    // footprint: fixed = rowptr + dinv + csr (+ padding), buffers = 2 * N*128*sizeof(T)
    size_t fixed   = ((size_t)(N + 1) * 4 + 256) + ((size_t)N * 4 + 256) + ((size_t)E * 4 + 256);
    size_t need32  = fixed + 2 * ((size_t)N * 128 * 4 + 256);
    size_t need16  = fixed + 2 * ((size_t)N * 128 * 2 + 256);

    if (ws_size >= need32) {
        run_pipeline<float>(x, src, dst, batch, W1, b1, W2, b2, W3, b3, out,
                            N, E, G, (char*)d_ws, stream);
    } else if (ws_size >= need16) {
        run_pipeline<__hip_bfloat16>(x, src, dst, batch, W1, b1, W2, b2, W3, b3, out,
                                     N, E, G, (char*)d_ws, stream);
    } else {
        // not enough scratch: clean, crash-free failure signature
        hipMemsetAsync(d_out, 0, (size_t)out_size * 4, stream);
    }
}

// Round 5
// 974.007 us; speedup vs baseline: 1.7681x; 1.7681x over previous
//
#include <hip/hip_runtime.h>
#include <hip/hip_bf16.h>

// GCN: 3x (h = relu( dinv .* Agg( dinv .* (h@W) ) + b)) then mean-pool by graph.
// Agg = sum over in-edges (CSR by dst) + self loop.
// h buffers: fp32. s (gather source) buffers: bf16 (halves gather traffic).
// Matmuls 2/3: MFMA bf16 with hi/lo split (3 mfma) -> fp32-accurate.

typedef __attribute__((ext_vector_type(8))) __bf16 bf16x8;
typedef __attribute__((ext_vector_type(4))) float f32x4;

union BF8 { bf16x8 v; unsigned short u[8]; };

__device__ inline unsigned short f2bf(float f) {
    union { float f; unsigned u; } x; x.f = f;
    unsigned r = (x.u + 0x7FFFu + ((x.u >> 16) & 1u)) >> 16;
    return (unsigned short)r;
}
__device__ inline float bf2f(unsigned short u) {
    union { float f; unsigned u; } x; x.u = ((unsigned)u) << 16;
    return x.f;
}
__device__ inline float2 ld2bf(const unsigned short* p, size_t pair_idx) {
    unsigned v = ((const unsigned*)p)[pair_idx];
    union { float f; unsigned u; } a, b;
    a.u = (v & 0xFFFFu) << 16;
    b.u = v & 0xFFFF0000u;
    return make_float2(a.f, b.f);
}

// ---------------- CSR build ----------------

__global__ __launch_bounds__(256) void degree_kernel(const int* __restrict__ dst,
                                                     int* __restrict__ count, int E) {
    int e = blockIdx.x * blockDim.x + threadIdx.x;
    if (e < E) atomicAdd(&count[dst[e]], 1);
}

__global__ __launch_bounds__(1024) void scan_kernel(const int* __restrict__ count,
                                                    int* __restrict__ rowptr,
                                                    int* __restrict__ cur,
                                                    float* __restrict__ dinv, int N) {
    __shared__ int ssum[1024];
    const int t = threadIdx.x;
    const int C = (N + 1023) >> 10;
    const int lo = t * C;
    const int hi = min(lo + C, N);
    int s = 0;
    for (int i = lo; i < hi; ++i) s += count[i];
    ssum[t] = s;
    __syncthreads();
    if (t == 0) {
        int run = 0;
        for (int k = 0; k < 1024; ++k) { int v = ssum[k]; ssum[k] = run; run += v; }
        rowptr[N] = run;
    }
    __syncthreads();
    int run = ssum[t];
    for (int i = lo; i < hi; ++i) {
        rowptr[i] = run;
        cur[i]    = run;
        float dg  = (float)count[i] + 1.0f;   // +1 self loop
        dinv[i]   = rsqrtf(dg);
        run += count[i];
    }
}

__global__ __launch_bounds__(256) void fill_kernel(const int* __restrict__ src,
                                                   const int* __restrict__ dst,
                                                   int* __restrict__ cur,
                                                   int* __restrict__ csr, int E) {
    int e = blockIdx.x * blockDim.x + threadIdx.x;
    if (e < E) {
        int p = atomicAdd(&cur[dst[e]], 1);
        csr[p] = src[e];
    }
}

// ---------------- W transpose + hi/lo bf16 split ----------------
// WT tables layout: [which][hi/lo][col][k], each 128x128 ushort.

__global__ __launch_bounds__(256) void wsplit_kernel(const float* __restrict__ W2,
                                                     const float* __restrict__ W3,
                                                     unsigned short* __restrict__ WT) {
    int t = blockIdx.x * blockDim.x + threadIdx.x;   // 0 .. 32767
    int which = t >> 14;
    int idx = t & 16383;
    int k = idx >> 7, c = idx & 127;
    const float* W = which ? W3 : W2;
    float w = W[k * 128 + c];
    unsigned short hi = f2bf(w);
    unsigned short lo = f2bf(w - bf2f(hi));
    unsigned short* Th = WT + (size_t)which * 2 * 16384;
    unsigned short* Tl = Th + 16384;
    Th[c * 128 + k] = hi;
    Tl[c * 128 + k] = lo;
}

// ---------------- layer-1 matmul (K=26, fp32, s = dinv*(x@W1) -> bf16) -------

__global__ __launch_bounds__(256) void matmul1_kernel(const float* __restrict__ x,
                                                      const float* __restrict__ W,
                                                      const float* __restrict__ dinv,
                                                      unsigned short* __restrict__ s, int N) {
    int gid = blockIdx.x * blockDim.x + threadIdx.x;
    int row = gid >> 7, col = gid & 127;
    if (row >= N) return;
    float acc = 0.f;
    const float* xr = x + (size_t)row * 26;
#pragma unroll
    for (int k = 0; k < 26; ++k) acc = fmaf(xr[k], W[k * 128 + col], acc);
    s[(size_t)row * 128 + col] = f2bf(acc * dinv[row]);
}

// ---------------- MFMA matmul: s = dinv * (h @ W), h fp32, s bf16 ------------
// Per wave: 16 rows x 128 cols. A from h (fp32->hi/lo bf16 in-kernel),
// B from pre-split WT tables (L1-resident). 3 MFMAs per (ks, ct).

__global__ __launch_bounds__(256) void mm_mfma_kernel(const float* __restrict__ h,
                                                      const unsigned short* __restrict__ WTh,
                                                      const unsigned short* __restrict__ WTl,
                                                      const float* __restrict__ dinv,
                                                      unsigned short* __restrict__ s, int N) {
    int wave = threadIdx.x >> 6;
    int lane = threadIdx.x & 63;
    int r0 = blockIdx.x * 64 + wave * 16;
    int arow = r0 + (lane & 15);
    int acl = min(arow, N - 1);
    int kgrp = lane >> 4;                       // 0..3
    const float* hrow = h + (size_t)acl * 128 + kgrp * 8;

    f32x4 acc[8];
#pragma unroll
    for (int i = 0; i < 8; ++i) acc[i] = f32x4{0.f, 0.f, 0.f, 0.f};

    const unsigned short* bh_base = WTh + (size_t)(lane & 15) * 128 + kgrp * 8;
    const unsigned short* bl_base = WTl + (size_t)(lane & 15) * 128 + kgrp * 8;

#pragma unroll
    for (int ks = 0; ks < 4; ++ks) {
        const float4* p = (const float4*)(hrow + ks * 32);
        float4 v0 = p[0], v1 = p[1];
        float va[8] = {v0.x, v0.y, v0.z, v0.w, v1.x, v1.y, v1.z, v1.w};
        BF8 ah, al;
#pragma unroll
        for (int j = 0; j < 8; ++j) {
            unsigned short hb = f2bf(va[j]);
            ah.u[j] = hb;
            al.u[j] = f2bf(va[j] - bf2f(hb));
        }
#pragma unroll
        for (int ct = 0; ct < 8; ++ct) {
            BF8 bh, bl;
            bh.v = *(const bf16x8*)(bh_base + ks * 32 + (size_t)ct * 16 * 128);
            bl.v = *(const bf16x8*)(bl_base + ks * 32 + (size_t)ct * 16 * 128);
            acc[ct] = __builtin_amdgcn_mfma_f32_16x16x32_bf16(ah.v, bh.v, acc[ct], 0, 0, 0);
            acc[ct] = __builtin_amdgcn_mfma_f32_16x16x32_bf16(al.v, bh.v, acc[ct], 0, 0, 0);
            acc[ct] = __builtin_amdgcn_mfma_f32_16x16x32_bf16(ah.v, bl.v, acc[ct], 0, 0, 0);
        }
    }

    // epilogue: C/D layout col=lane&15, row=(lane>>4)*4+reg (verified layout)
    int rbase = r0 + (lane >> 4) * 4;
#pragma unroll
    for (int r = 0; r < 4; ++r) {
        int row = rbase + r;
        if (row < N) {
            float di = dinv[row];
#pragma unroll
            for (int ct = 0; ct < 8; ++ct) {
                int col = ct * 16 + (lane & 15);
                s[(size_t)row * 128 + col] = f2bf(acc[ct][r] * di);
            }
        }
    }
}

// ---------------- aggregation: one wave per node, bf16 gather ----------------

template <int RELU>
__global__ __launch_bounds__(256) void aggregate_kernel(const unsigned short* __restrict__ s,
                                                        const float* __restrict__ dinv,
                                                        const int* __restrict__ rowptr,
                                                        const int* __restrict__ csr,
                                                        const float* __restrict__ bias,
                                                        float* __restrict__ hout, int N) {
    int wid  = (int)((blockIdx.x * blockDim.x + threadIdx.x) >> 6);
    int lane = threadIdx.x & 63;
    if (wid >= N) return;
    const int i = wid;
    int start = __builtin_amdgcn_readfirstlane(rowptr[i]);
    int end   = __builtin_amdgcn_readfirstlane(rowptr[i + 1]);
    float2 acc = ld2bf(s, (size_t)i * 64 + lane);      // self-loop term
    int e = start;
    for (; e + 8 <= end; e += 8) {
        int idx[8];
#pragma unroll
        for (int j = 0; j < 8; ++j) idx[j] = csr[e + j];
#pragma unroll
        for (int j = 0; j < 8; ++j) {
            float2 v = ld2bf(s, (size_t)idx[j] * 64 + lane);
            acc.x += v.x; acc.y += v.y;
        }
    }
    for (; e < end; ++e) {
        int sn = csr[e];
        float2 v = ld2bf(s, (size_t)sn * 64 + lane);
        acc.x += v.x; acc.y += v.y;
    }
    float di = dinv[i];
    float2 bv = ((const float2*)bias)[lane];
    float ox = acc.x * di + bv.x;
    float oy = acc.y * di + bv.y;
    if (RELU) { ox = fmaxf(ox, 0.f); oy = fmaxf(oy, 0.f); }
    ((float2*)hout)[(size_t)i * 64 + lane] = make_float2(ox, oy);
}

// ---------------- mean pool (fp32 h) ----------------

__global__ __launch_bounds__(128) void pool_kernel(const float* __restrict__ h,
                                                   const int* __restrict__ batch,
                                                   float* __restrict__ out, int N) {
    int g = blockIdx.x;
    int j = threadIdx.x;
    int lo = 0, hi = N;
    while (lo < hi) { int mid = (lo + hi) >> 1; if (batch[mid] < g) lo = mid + 1; else hi = mid; }
    int start = lo;
    hi = N;
    while (lo < hi) { int mid = (lo + hi) >> 1; if (batch[mid] < g + 1) lo = mid + 1; else hi = mid; }
    int end = lo;
    float acc = 0.f;
    for (int i = start; i < end; ++i) acc += h[(size_t)i * 128 + j];
    int cnt = end - start;
    out[(size_t)g * 128 + j] = acc / (float)max(cnt, 1);
}

// ---------------- driver ----------------

extern "C" void kernel_launch(void* const* d_in, const int* in_sizes, int n_in,
                              void* d_out, int out_size, void* d_ws, size_t ws_size,
                              hipStream_t stream) {
    const float* x     = (const float*)d_in[0];
    const int*   edge  = (const int*)d_in[1];
    const int*   batch = (const int*)d_in[2];
    const float* W1    = (const float*)d_in[3];
    const float* b1    = (const float*)d_in[4];
    const float* W2    = (const float*)d_in[5];
    const float* b2    = (const float*)d_in[6];
    const float* W3    = (const float*)d_in[7];
    const float* b3    = (const float*)d_in[8];
    float* out = (float*)d_out;

    const int N = in_sizes[2];
    const int E = in_sizes[1] / 2;
    const int G = out_size / 128;

    const int* src = edge;
    const int* dst = edge + E;

    char* base = (char*)d_ws;
    size_t off = 0;
    auto carve = [&](size_t bytes) -> char* {
        char* p = base + off;
        off = (off + bytes + 255) & ~(size_t)255;
        return p;
    };
    int*            rowptr = (int*)carve((size_t)(N + 1) * 4);
    float*          dinv   = (float*)carve((size_t)N * 4);
    int*            csr    = (int*)carve((size_t)E * 4);
    unsigned short* WT     = (unsigned short*)carve((size_t)4 * 16384 * 2);
    float*          bufH   = (float*)carve((size_t)N * 128 * 4);           // fp32 h
    unsigned short* bufS   = (unsigned short*)carve((size_t)N * 128 * 2);  // bf16 s

    if (off > ws_size) {  // needs ~84 MB; round-2 fp32 path (110 MB) ran fine
        hipMemsetAsync(d_out, 0, (size_t)out_size * 4, stream);
        return;
    }

    // count/cur live only during CSR build, before bufH/bufS are written
    int* count = (int*)bufH;
    int* cur   = (int*)bufS;

    hipMemsetAsync(count, 0, (size_t)N * 4, stream);

    int ebk = (E + 255) / 256;
    degree_kernel<<<ebk, 256, 0, stream>>>(dst, count, E);
    scan_kernel<<<1, 1024, 0, stream>>>(count, rowptr, cur, dinv, N);
    fill_kernel<<<ebk, 256, 0, stream>>>(src, dst, cur, csr, E);
    wsplit_kernel<<<128, 256, 0, stream>>>(W2, W3, WT);

    const unsigned short* WT2h = WT;
    const unsigned short* WT2l = WT + 16384;
    const unsigned short* WT3h = WT + 2 * 16384;
    const unsigned short* WT3l = WT + 3 * 16384;

    int mmbk  = (N * 128 + 255) / 256;
    int mfbk  = (N + 63) / 64;
    int agbk  = (N + 3) / 4;

    // layer 1 (fp32 math, K=26)
    matmul1_kernel<<<mmbk, 256, 0, stream>>>(x, W1, dinv, bufS, N);
    aggregate_kernel<1><<<agbk, 256, 0, stream>>>(bufS, dinv, rowptr, csr, b1, bufH, N);
    // layer 2
    mm_mfma_kernel<<<mfbk, 256, 0, stream>>>(bufH, WT2h, WT2l, dinv, bufS, N);
    aggregate_kernel<1><<<agbk, 256, 0, stream>>>(bufS, dinv, rowptr, csr, b2, bufH, N);
    // layer 3
    mm_mfma_kernel<<<mfbk, 256, 0, stream>>>(bufH, WT3h, WT3l, dinv, bufS, N);
    aggregate_kernel<0><<<agbk, 256, 0, stream>>>(bufS, dinv, rowptr, csr, b3, bufH, N);
    // pool
    pool_kernel<<<G, 128, 0, stream>>>(bufH, batch, out, N);
}

// Round 6
// 701.984 us; speedup vs baseline: 2.4533x; 1.3875x over previous
//
#include <hip/hip_runtime.h>
#include <hip/hip_bf16.h>

// GCN: 3x (h = relu( dinv .* Agg( dinv .* (h@W) ) + b)) then mean-pool by graph.
// Agg = sum over in-edges (CSR by dst) + self loop.
// h buffers: fp32. s (gather source) buffers: bf16 (halves gather traffic).
// Matmuls 2/3: MFMA bf16 with hi/lo split (3 mfma) -> fp32-accurate.
// CSR prefix scan: two-level multi-block scan (round-5 fix: old single-block
// scan_kernel was 287us at 0.15% occupancy).

typedef __attribute__((ext_vector_type(8))) __bf16 bf16x8;
typedef __attribute__((ext_vector_type(4))) float f32x4;

union BF8 { bf16x8 v; unsigned short u[8]; };

__device__ inline unsigned short f2bf(float f) {
    union { float f; unsigned u; } x; x.f = f;
    unsigned r = (x.u + 0x7FFFu + ((x.u >> 16) & 1u)) >> 16;
    return (unsigned short)r;
}
__device__ inline float bf2f(unsigned short u) {
    union { float f; unsigned u; } x; x.u = ((unsigned)u) << 16;
    return x.f;
}
__device__ inline float2 ld2bf(const unsigned short* p, size_t pair_idx) {
    unsigned v = ((const unsigned*)p)[pair_idx];
    union { float f; unsigned u; } a, b;
    a.u = (v & 0xFFFFu) << 16;
    b.u = v & 0xFFFF0000u;
    return make_float2(a.f, b.f);
}

// ---------------- CSR build ----------------

__global__ __launch_bounds__(256) void degree_kernel(const int* __restrict__ dst,
                                                     int* __restrict__ count, int E) {
    int e = blockIdx.x * blockDim.x + threadIdx.x;
    if (e < E) atomicAdd(&count[dst[e]], 1);
}

// two-level scan: 512 elements per block, 256 threads (2 elems/thread)

__global__ __launch_bounds__(256) void scan_partial_kernel(const int* __restrict__ count,
                                                           int* __restrict__ blocksum, int N) {
    __shared__ int sd[256];
    int t = threadIdx.x, b = blockIdx.x;
    int i0 = b * 512 + t * 2;
    int c0 = (i0     < N) ? count[i0]     : 0;
    int c1 = (i0 + 1 < N) ? count[i0 + 1] : 0;
    sd[t] = c0 + c1;
    __syncthreads();
#pragma unroll
    for (int o = 1; o < 256; o <<= 1) {
        int v = (t >= o) ? sd[t - o] : 0;
        __syncthreads();
        sd[t] += v;
        __syncthreads();
    }
    if (t == 255) blocksum[b] = sd[255];
}

__global__ __launch_bounds__(256) void scan_blocks_kernel(const int* __restrict__ blocksum,
                                                          int* __restrict__ blockoff,
                                                          int* __restrict__ rowptrN, int NB) {
    __shared__ int sd[256];
    int t = threadIdx.x;
    int v = (t < NB) ? blocksum[t] : 0;
    sd[t] = v;
    __syncthreads();
#pragma unroll
    for (int o = 1; o < 256; o <<= 1) {
        int u = (t >= o) ? sd[t - o] : 0;
        __syncthreads();
        sd[t] += u;
        __syncthreads();
    }
    if (t < NB) blockoff[t] = sd[t] - v;     // exclusive block offset
    if (t == 255) *rowptrN = sd[255];        // total = E
}

__global__ __launch_bounds__(256) void scan_scatter_kernel(const int* __restrict__ count,
                                                           const int* __restrict__ blockoff,
                                                           int* __restrict__ rowptr,
                                                           int* __restrict__ cur,
                                                           float* __restrict__ dinv, int N) {
    __shared__ int sd[256];
    int t = threadIdx.x, b = blockIdx.x;
    int i0 = b * 512 + t * 2;
    int c0 = (i0     < N) ? count[i0]     : 0;
    int c1 = (i0 + 1 < N) ? count[i0 + 1] : 0;
    int s = c0 + c1;
    sd[t] = s;
    __syncthreads();
#pragma unroll
    for (int o = 1; o < 256; o <<= 1) {
        int v = (t >= o) ? sd[t - o] : 0;
        __syncthreads();
        sd[t] += v;
        __syncthreads();
    }
    int pos = blockoff[b] + sd[t] - s;       // exclusive prefix for elem i0
    if (i0 < N) {
        rowptr[i0] = pos; cur[i0] = pos;
        dinv[i0]   = rsqrtf((float)c0 + 1.0f);
        pos += c0;
    }
    if (i0 + 1 < N) {
        rowptr[i0 + 1] = pos; cur[i0 + 1] = pos;
        dinv[i0 + 1]   = rsqrtf((float)c1 + 1.0f);
    }
}

__global__ __launch_bounds__(256) void fill_kernel(const int* __restrict__ src,
                                                   const int* __restrict__ dst,
                                                   int* __restrict__ cur,
                                                   int* __restrict__ csr, int E) {
    int e = blockIdx.x * blockDim.x + threadIdx.x;
    if (e < E) {
        int p = atomicAdd(&cur[dst[e]], 1);
        csr[p] = src[e];
    }
}

// ---------------- W transpose + hi/lo bf16 split ----------------
// WT tables layout: [which][hi/lo][col][k], each 128x128 ushort.

__global__ __launch_bounds__(256) void wsplit_kernel(const float* __restrict__ W2,
                                                     const float* __restrict__ W3,
                                                     unsigned short* __restrict__ WT) {
    int t = blockIdx.x * blockDim.x + threadIdx.x;   // 0 .. 32767
    int which = t >> 14;
    int idx = t & 16383;
    int k = idx >> 7, c = idx & 127;
    const float* W = which ? W3 : W2;
    float w = W[k * 128 + c];
    unsigned short hi = f2bf(w);
    unsigned short lo = f2bf(w - bf2f(hi));
    unsigned short* Th = WT + (size_t)which * 2 * 16384;
    unsigned short* Tl = Th + 16384;
    Th[c * 128 + k] = hi;
    Tl[c * 128 + k] = lo;
}

// ---------------- layer-1 matmul (K=26, fp32, s = dinv*(x@W1) -> bf16) -------

__global__ __launch_bounds__(256) void matmul1_kernel(const float* __restrict__ x,
                                                      const float* __restrict__ W,
                                                      const float* __restrict__ dinv,
                                                      unsigned short* __restrict__ s, int N) {
    int gid = blockIdx.x * blockDim.x + threadIdx.x;
    int row = gid >> 7, col = gid & 127;
    if (row >= N) return;
    float acc = 0.f;
    const float* xr = x + (size_t)row * 26;
#pragma unroll
    for (int k = 0; k < 26; ++k) acc = fmaf(xr[k], W[k * 128 + col], acc);
    s[(size_t)row * 128 + col] = f2bf(acc * dinv[row]);
}

// ---------------- MFMA matmul: s = dinv * (h @ W), h fp32, s bf16 ------------

__global__ __launch_bounds__(256) void mm_mfma_kernel(const float* __restrict__ h,
                                                      const unsigned short* __restrict__ WTh,
                                                      const unsigned short* __restrict__ WTl,
                                                      const float* __restrict__ dinv,
                                                      unsigned short* __restrict__ s, int N) {
    int wave = threadIdx.x >> 6;
    int lane = threadIdx.x & 63;
    int r0 = blockIdx.x * 64 + wave * 16;
    int arow = r0 + (lane & 15);
    int acl = min(arow, N - 1);
    int kgrp = lane >> 4;                       // 0..3
    const float* hrow = h + (size_t)acl * 128 + kgrp * 8;

    f32x4 acc[8];
#pragma unroll
    for (int i = 0; i < 8; ++i) acc[i] = f32x4{0.f, 0.f, 0.f, 0.f};

    const unsigned short* bh_base = WTh + (size_t)(lane & 15) * 128 + kgrp * 8;
    const unsigned short* bl_base = WTl + (size_t)(lane & 15) * 128 + kgrp * 8;

#pragma unroll
    for (int ks = 0; ks < 4; ++ks) {
        const float4* p = (const float4*)(hrow + ks * 32);
        float4 v0 = p[0], v1 = p[1];
        float va[8] = {v0.x, v0.y, v0.z, v0.w, v1.x, v1.y, v1.z, v1.w};
        BF8 ah, al;
#pragma unroll
        for (int j = 0; j < 8; ++j) {
            unsigned short hb = f2bf(va[j]);
            ah.u[j] = hb;
            al.u[j] = f2bf(va[j] - bf2f(hb));
        }
#pragma unroll
        for (int ct = 0; ct < 8; ++ct) {
            BF8 bh, bl;
            bh.v = *(const bf16x8*)(bh_base + ks * 32 + (size_t)ct * 16 * 128);
            bl.v = *(const bf16x8*)(bl_base + ks * 32 + (size_t)ct * 16 * 128);
            acc[ct] = __builtin_amdgcn_mfma_f32_16x16x32_bf16(ah.v, bh.v, acc[ct], 0, 0, 0);
            acc[ct] = __builtin_amdgcn_mfma_f32_16x16x32_bf16(al.v, bh.v, acc[ct], 0, 0, 0);
            acc[ct] = __builtin_amdgcn_mfma_f32_16x16x32_bf16(ah.v, bl.v, acc[ct], 0, 0, 0);
        }
    }

    // C/D layout: col=lane&15, row=(lane>>4)*4+reg
    int rbase = r0 + (lane >> 4) * 4;
#pragma unroll
    for (int r = 0; r < 4; ++r) {
        int row = rbase + r;
        if (row < N) {
            float di = dinv[row];
#pragma unroll
            for (int ct = 0; ct < 8; ++ct) {
                int col = ct * 16 + (lane & 15);
                s[(size_t)row * 128 + col] = f2bf(acc[ct][r] * di);
            }
        }
    }
}

// ---------------- aggregation: one wave per node, bf16 gather ----------------

template <int RELU>
__global__ __launch_bounds__(256) void aggregate_kernel(const unsigned short* __restrict__ s,
                                                        const float* __restrict__ dinv,
                                                        const int* __restrict__ rowptr,
                                                        const int* __restrict__ csr,
                                                        const float* __restrict__ bias,
                                                        float* __restrict__ hout, int N) {
    int wid  = (int)((blockIdx.x * blockDim.x + threadIdx.x) >> 6);
    int lane = threadIdx.x & 63;
    if (wid >= N) return;
    const int i = wid;
    int start = __builtin_amdgcn_readfirstlane(rowptr[i]);
    int end   = __builtin_amdgcn_readfirstlane(rowptr[i + 1]);
    float2 acc = ld2bf(s, (size_t)i * 64 + lane);      // self-loop term
    int e = start;
    for (; e + 8 <= end; e += 8) {
        int idx[8];
#pragma unroll
        for (int j = 0; j < 8; ++j) idx[j] = csr[e + j];
#pragma unroll
        for (int j = 0; j < 8; ++j) {
            float2 v = ld2bf(s, (size_t)idx[j] * 64 + lane);
            acc.x += v.x; acc.y += v.y;
        }
    }
    for (; e < end; ++e) {
        int sn = csr[e];
        float2 v = ld2bf(s, (size_t)sn * 64 + lane);
        acc.x += v.x; acc.y += v.y;
    }
    float di = dinv[i];
    float2 bv = ((const float2*)bias)[lane];
    float ox = acc.x * di + bv.x;
    float oy = acc.y * di + bv.y;
    if (RELU) { ox = fmaxf(ox, 0.f); oy = fmaxf(oy, 0.f); }
    ((float2*)hout)[(size_t)i * 64 + lane] = make_float2(ox, oy);
}

// ---------------- mean pool (fp32 h) ----------------

__global__ __launch_bounds__(128) void pool_kernel(const float* __restrict__ h,
                                                   const int* __restrict__ batch,
                                                   float* __restrict__ out, int N) {
    int g = blockIdx.x;
    int j = threadIdx.x;
    int lo = 0, hi = N;
    while (lo < hi) { int mid = (lo + hi) >> 1; if (batch[mid] < g) lo = mid + 1; else hi = mid; }
    int start = lo;
    hi = N;
    while (lo < hi) { int mid = (lo + hi) >> 1; if (batch[mid] < g + 1) lo = mid + 1; else hi = mid; }
    int end = lo;
    float acc = 0.f;
    for (int i = start; i < end; ++i) acc += h[(size_t)i * 128 + j];
    int cnt = end - start;
    out[(size_t)g * 128 + j] = acc / (float)max(cnt, 1);
}

// ---------------- driver ----------------

extern "C" void kernel_launch(void* const* d_in, const int* in_sizes, int n_in,
                              void* d_out, int out_size, void* d_ws, size_t ws_size,
                              hipStream_t stream) {
    const float* x     = (const float*)d_in[0];
    const int*   edge  = (const int*)d_in[1];
    const int*   batch = (const int*)d_in[2];
    const float* W1    = (const float*)d_in[3];
    const float* b1    = (const float*)d_in[4];
    const float* W2    = (const float*)d_in[5];
    const float* b2    = (const float*)d_in[6];
    const float* W3    = (const float*)d_in[7];
    const float* b3    = (const float*)d_in[8];
    float* out = (float*)d_out;

    const int N = in_sizes[2];
    const int E = in_sizes[1] / 2;
    const int G = out_size / 128;

    const int* src = edge;
    const int* dst = edge + E;

    char* base = (char*)d_ws;
    size_t off = 0;
    auto carve = [&](size_t bytes) -> char* {
        char* p = base + off;
        off = (off + bytes + 255) & ~(size_t)255;
        return p;
    };
    int*            rowptr   = (int*)carve((size_t)(N + 1) * 4);
    float*          dinv     = (float*)carve((size_t)N * 4);
    int*            csr      = (int*)carve((size_t)E * 4);
    unsigned short* WT       = (unsigned short*)carve((size_t)4 * 16384 * 2);
    int*            blocksum = (int*)carve(1024);
    int*            blockoff = (int*)carve(1024);
    float*          bufH     = (float*)carve((size_t)N * 128 * 4);           // fp32 h
    unsigned short* bufS     = (unsigned short*)carve((size_t)N * 128 * 2);  // bf16 s

    if (off > ws_size) {
        hipMemsetAsync(d_out, 0, (size_t)out_size * 4, stream);
        return;
    }

    // count/cur live only during CSR build, before bufH/bufS are written
    int* count = (int*)bufH;
    int* cur   = (int*)bufS;

    hipMemsetAsync(count, 0, (size_t)N * 4, stream);

    const int NB = (N + 511) / 512;     // 196 for N=100000 (must be <= 256)
    int ebk = (E + 255) / 256;
    degree_kernel<<<ebk, 256, 0, stream>>>(dst, count, E);
    scan_partial_kernel<<<NB, 256, 0, stream>>>(count, blocksum, N);
    scan_blocks_kernel<<<1, 256, 0, stream>>>(blocksum, blockoff, rowptr + N, NB);
    scan_scatter_kernel<<<NB, 256, 0, stream>>>(count, blockoff, rowptr, cur, dinv, N);
    fill_kernel<<<ebk, 256, 0, stream>>>(src, dst, cur, csr, E);
    wsplit_kernel<<<128, 256, 0, stream>>>(W2, W3, WT);

    const unsigned short* WT2h = WT;
    const unsigned short* WT2l = WT + 16384;
    const unsigned short* WT3h = WT + 2 * 16384;
    const unsigned short* WT3l = WT + 3 * 16384;

    int mmbk  = (N * 128 + 255) / 256;
    int mfbk  = (N + 63) / 64;
    int agbk  = (N + 3) / 4;

    // layer 1 (fp32 math, K=26)
    matmul1_kernel<<<mmbk, 256, 0, stream>>>(x, W1, dinv, bufS, N);
    aggregate_kernel<1><<<agbk, 256, 0, stream>>>(bufS, dinv, rowptr, csr, b1, bufH, N);
    // layer 2
    mm_mfma_kernel<<<mfbk, 256, 0, stream>>>(bufH, WT2h, WT2l, dinv, bufS, N);
    aggregate_kernel<1><<<agbk, 256, 0, stream>>>(bufS, dinv, rowptr, csr, b2, bufH, N);
    // layer 3
    mm_mfma_kernel<<<mfbk, 256, 0, stream>>>(bufH, WT3h, WT3l, dinv, bufS, N);
    aggregate_kernel<0><<<agbk, 256, 0, stream>>>(bufS, dinv, rowptr, csr, b3, bufH, N);
    // pool
    pool_kernel<<<G, 128, 0, stream>>>(bufH, batch, out, N);
}

// Round 7
// 565.746 us; speedup vs baseline: 3.0440x; 1.2408x over previous
//
#include <hip/hip_runtime.h>
#include <hip/hip_bf16.h>

// GCN: 3x (h = relu( dinv .* Agg( dinv .* (h@W) ) + b)) then mean-pool by graph.
// CSR build: bucketed counting sort (196 buckets of 512 nodes) -> line-granular
// writes (round-6 fix: fill_kernel's random 4B scatter caused 105MB WRITE_SIZE).
// Layer 1: aggregate in 26-dim x-space (Agg commutes with @W1), then matmul.
// Layers 2/3: MFMA bf16 hi/lo split matmul (fp32-accurate), bf16 gather table.

typedef __attribute__((ext_vector_type(8))) __bf16 bf16x8;
typedef __attribute__((ext_vector_type(4))) float f32x4;

union BF8 { bf16x8 v; unsigned short u[8]; };

#define BKT_SHIFT 9
#define BKT_NODES 512
#define EPB 8192               // edges per block in bucket passes

__device__ inline unsigned short f2bf(float f) {
    union { float f; unsigned u; } x; x.f = f;
    unsigned r = (x.u + 0x7FFFu + ((x.u >> 16) & 1u)) >> 16;
    return (unsigned short)r;
}
__device__ inline float bf2f(unsigned short u) {
    union { float f; unsigned u; } x; x.u = ((unsigned)u) << 16;
    return x.f;
}
__device__ inline float2 ld2bf(const unsigned short* p, size_t pair_idx) {
    unsigned v = ((const unsigned*)p)[pair_idx];
    union { float f; unsigned u; } a, b;
    a.u = (v & 0xFFFFu) << 16;
    b.u = v & 0xFFFF0000u;
    return make_float2(a.f, b.f);
}

// ---------------- CSR build: bucketed counting sort ----------------

__global__ __launch_bounds__(256) void bucket_hist_kernel(const int* __restrict__ dst,
                                                          int* __restrict__ bcount, int E) {
    __shared__ int lh[256];
    int t = threadIdx.x;
    lh[t] = 0;
    __syncthreads();
    int base = blockIdx.x * EPB;
    for (int i = t; i < EPB; i += 256) {
        int e = base + i;
        if (e < E) atomicAdd(&lh[dst[e] >> BKT_SHIFT], 1);
    }
    __syncthreads();
    if (lh[t]) atomicAdd(&bcount[t], lh[t]);
}

__global__ __launch_bounds__(256) void scan_buckets_kernel(const int* __restrict__ bcount,
                                                           int* __restrict__ blockoff,
                                                           int* __restrict__ bucket_cur, int NB) {
    __shared__ int sd[256];
    int t = threadIdx.x;
    int v = (t < NB) ? bcount[t] : 0;
    sd[t] = v;
    __syncthreads();
#pragma unroll
    for (int o = 1; o < 256; o <<= 1) {
        int u = (t >= o) ? sd[t - o] : 0;
        __syncthreads();
        sd[t] += u;
        __syncthreads();
    }
    if (t < NB) { int ex = sd[t] - v; blockoff[t] = ex; bucket_cur[t] = ex; }
    if (t == 255) blockoff[NB] = sd[255];   // = E
}

// scatter edges into bucket-grouped ebuf; rec = src | ((dst&511)<<20)
__global__ __launch_bounds__(256) void bucket_scatter_kernel(const int* __restrict__ src,
                                                             const int* __restrict__ dst,
                                                             int* __restrict__ bucket_cur,
                                                             int* __restrict__ ebuf, int E) {
    __shared__ int lh[256];
    __shared__ int lb[256];
    int t = threadIdx.x;
    lh[t] = 0;
    __syncthreads();
    int base = blockIdx.x * EPB;
    for (int i = t; i < EPB; i += 256) {
        int e = base + i;
        if (e < E) atomicAdd(&lh[dst[e] >> BKT_SHIFT], 1);
    }
    __syncthreads();
    int n = lh[t];
    if (n) lb[t] = atomicAdd(&bucket_cur[t], n);
    lh[t] = 0;
    __syncthreads();
    for (int i = t; i < EPB; i += 256) {
        int e = base + i;
        if (e < E) {
            int d = dst[e];
            int k = d >> BKT_SHIFT;
            int r = atomicAdd(&lh[k], 1);
            ebuf[lb[k] + r] = src[e] | ((d & (BKT_NODES - 1)) << 20);
        }
    }
}

// per-bucket CSR finalize: node counts, rowptr, dinv, sorted csr (src ids)
__global__ __launch_bounds__(256) void bucket_csr_kernel(const int* __restrict__ ebuf,
                                                         const int* __restrict__ blockoff,
                                                         int* __restrict__ rowptr,
                                                         float* __restrict__ dinv,
                                                         int* __restrict__ csr, int N, int NB) {
    __shared__ int cnt[BKT_NODES];
    __shared__ int sd[256];
    int b = blockIdx.x, t = threadIdx.x;
    int node0 = b * BKT_NODES;
    int nn = min(BKT_NODES, N - node0);
    int ebase = blockoff[b];
    int ecnt = blockoff[b + 1] - ebase;
    cnt[t] = 0; cnt[t + 256] = 0;
    __syncthreads();
    for (int i = t; i < ecnt; i += 256)
        atomicAdd(&cnt[ebuf[ebase + i] >> 20], 1);
    __syncthreads();
    int c0 = cnt[2 * t], c1 = cnt[2 * t + 1];
    sd[t] = c0 + c1;
    __syncthreads();
#pragma unroll
    for (int o = 1; o < 256; o <<= 1) {
        int u = (t >= o) ? sd[t - o] : 0;
        __syncthreads();
        sd[t] += u;
        __syncthreads();
    }
    int ex = sd[t] - c0 - c1;                       // exclusive prefix for node 2t
    if (2 * t < nn) {
        rowptr[node0 + 2 * t] = ebase + ex;
        dinv[node0 + 2 * t]   = rsqrtf((float)c0 + 1.0f);
    }
    if (2 * t + 1 < nn) {
        rowptr[node0 + 2 * t + 1] = ebase + ex + c0;
        dinv[node0 + 2 * t + 1]   = rsqrtf((float)c1 + 1.0f);
    }
    if (b == NB - 1 && t == 0) rowptr[N] = ebase + ecnt;   // = E
    __syncthreads();            // all cnt reads done
    cnt[2 * t] = ex;            // reuse cnt as scatter cursor
    cnt[2 * t + 1] = ex + c0;
    __syncthreads();
    for (int i = t; i < ecnt; i += 256) {
        int rec = ebuf[ebase + i];
        int p = atomicAdd(&cnt[rec >> 20], 1);
        csr[ebase + p] = rec & 0xFFFFF;
    }
}

// ---------------- W transpose + hi/lo bf16 split ----------------

__global__ __launch_bounds__(256) void wsplit_kernel(const float* __restrict__ W2,
                                                     const float* __restrict__ W3,
                                                     unsigned short* __restrict__ WT) {
    int t = blockIdx.x * blockDim.x + threadIdx.x;   // 0 .. 32767
    int which = t >> 14;
    int idx = t & 16383;
    int k = idx >> 7, c = idx & 127;
    const float* W = which ? W3 : W2;
    float w = W[k * 128 + c];
    unsigned short hi = f2bf(w);
    unsigned short lo = f2bf(w - bf2f(hi));
    unsigned short* Th = WT + (size_t)which * 2 * 16384;
    unsigned short* Tl = Th + 16384;
    Th[c * 128 + k] = hi;
    Tl[c * 128 + k] = lo;
}

// ---------------- layer 1: aggregate in 26-dim x-space ----------------
// y[i] = dinv[i] * ( dinv[i]*x[i] + sum_{src->i} dinv[src]*x[src] )

__global__ __launch_bounds__(256) void aggx_kernel(const float* __restrict__ x,
                                                   const float* __restrict__ dinv,
                                                   const int* __restrict__ rowptr,
                                                   const int* __restrict__ csr,
                                                   float* __restrict__ y, int N) {
    int wid  = (int)((blockIdx.x * blockDim.x + threadIdx.x) >> 6);
    int lane = threadIdx.x & 63;
    if (wid >= N) return;
    const int i = wid;
    int start = __builtin_amdgcn_readfirstlane(rowptr[i]);
    int end   = __builtin_amdgcn_readfirstlane(rowptr[i + 1]);
    float di = dinv[i];
    float xv = (lane < 26) ? x[(size_t)i * 26 + lane] : 0.f;
    float acc = di * xv;
    int e = start;
    for (; e + 8 <= end; e += 8) {
        int idx[8];
#pragma unroll
        for (int j = 0; j < 8; ++j) idx[j] = csr[e + j];
#pragma unroll
        for (int j = 0; j < 8; ++j) {
            float v = (lane < 26) ? x[(size_t)idx[j] * 26 + lane] : 0.f;
            acc = fmaf(dinv[idx[j]], v, acc);
        }
    }
    for (; e < end; ++e) {
        int sn = csr[e];
        float v = (lane < 26) ? x[(size_t)sn * 26 + lane] : 0.f;
        acc = fmaf(dinv[sn], v, acc);
    }
    if (lane < 26) y[(size_t)i * 26 + lane] = acc * di;
}

// h1 = relu(y @ W1 + b1), fp32
__global__ __launch_bounds__(256) void matmul1b_kernel(const float* __restrict__ y,
                                                       const float* __restrict__ W1,
                                                       const float* __restrict__ b1,
                                                       float* __restrict__ h, int N) {
    int gid = blockIdx.x * blockDim.x + threadIdx.x;
    int row = gid >> 7, col = gid & 127;
    if (row >= N) return;
    float acc = b1[col];
    const float* yr = y + (size_t)row * 26;
#pragma unroll
    for (int k = 0; k < 26; ++k) acc = fmaf(yr[k], W1[k * 128 + col], acc);
    h[(size_t)row * 128 + col] = fmaxf(acc, 0.f);
}

// ---------------- MFMA matmul: s = dinv * (h @ W), h fp32, s bf16 ------------

__global__ __launch_bounds__(256) void mm_mfma_kernel(const float* __restrict__ h,
                                                      const unsigned short* __restrict__ WTh,
                                                      const unsigned short* __restrict__ WTl,
                                                      const float* __restrict__ dinv,
                                                      unsigned short* __restrict__ s, int N) {
    int wave = threadIdx.x >> 6;
    int lane = threadIdx.x & 63;
    int r0 = blockIdx.x * 64 + wave * 16;
    int arow = r0 + (lane & 15);
    int acl = min(arow, N - 1);
    int kgrp = lane >> 4;                       // 0..3
    const float* hrow = h + (size_t)acl * 128 + kgrp * 8;

    f32x4 acc[8];
#pragma unroll
    for (int i = 0; i < 8; ++i) acc[i] = f32x4{0.f, 0.f, 0.f, 0.f};

    const unsigned short* bh_base = WTh + (size_t)(lane & 15) * 128 + kgrp * 8;
    const unsigned short* bl_base = WTl + (size_t)(lane & 15) * 128 + kgrp * 8;

#pragma unroll
    for (int ks = 0; ks < 4; ++ks) {
        const float4* p = (const float4*)(hrow + ks * 32);
        float4 v0 = p[0], v1 = p[1];
        float va[8] = {v0.x, v0.y, v0.z, v0.w, v1.x, v1.y, v1.z, v1.w};
        BF8 ah, al;
#pragma unroll
        for (int j = 0; j < 8; ++j) {
            unsigned short hb = f2bf(va[j]);
            ah.u[j] = hb;
            al.u[j] = f2bf(va[j] - bf2f(hb));
        }
#pragma unroll
        for (int ct = 0; ct < 8; ++ct) {
            BF8 bh, bl;
            bh.v = *(const bf16x8*)(bh_base + ks * 32 + (size_t)ct * 16 * 128);
            bl.v = *(const bf16x8*)(bl_base + ks * 32 + (size_t)ct * 16 * 128);
            acc[ct] = __builtin_amdgcn_mfma_f32_16x16x32_bf16(ah.v, bh.v, acc[ct], 0, 0, 0);
            acc[ct] = __builtin_amdgcn_mfma_f32_16x16x32_bf16(al.v, bh.v, acc[ct], 0, 0, 0);
            acc[ct] = __builtin_amdgcn_mfma_f32_16x16x32_bf16(ah.v, bl.v, acc[ct], 0, 0, 0);
        }
    }

    // C/D layout: col=lane&15, row=(lane>>4)*4+reg
    int rbase = r0 + (lane >> 4) * 4;
#pragma unroll
    for (int r = 0; r < 4; ++r) {
        int row = rbase + r;
        if (row < N) {
            float di = dinv[row];
#pragma unroll
            for (int ct = 0; ct < 8; ++ct) {
                int col = ct * 16 + (lane & 15);
                s[(size_t)row * 128 + col] = f2bf(acc[ct][r] * di);
            }
        }
    }
}

// ---------------- aggregation: one wave per node, bf16 gather ----------------

template <int RELU>
__global__ __launch_bounds__(256) void aggregate_kernel(const unsigned short* __restrict__ s,
                                                        const float* __restrict__ dinv,
                                                        const int* __restrict__ rowptr,
                                                        const int* __restrict__ csr,
                                                        const float* __restrict__ bias,
                                                        float* __restrict__ hout, int N) {
    int wid  = (int)((blockIdx.x * blockDim.x + threadIdx.x) >> 6);
    int lane = threadIdx.x & 63;
    if (wid >= N) return;
    const int i = wid;
    int start = __builtin_amdgcn_readfirstlane(rowptr[i]);
    int end   = __builtin_amdgcn_readfirstlane(rowptr[i + 1]);
    float2 acc = ld2bf(s, (size_t)i * 64 + lane);      // self-loop term
    int e = start;
    for (; e + 8 <= end; e += 8) {
        int idx[8];
#pragma unroll
        for (int j = 0; j < 8; ++j) idx[j] = csr[e + j];
#pragma unroll
        for (int j = 0; j < 8; ++j) {
            float2 v = ld2bf(s, (size_t)idx[j] * 64 + lane);
            acc.x += v.x; acc.y += v.y;
        }
    }
    for (; e < end; ++e) {
        int sn = csr[e];
        float2 v = ld2bf(s, (size_t)sn * 64 + lane);
        acc.x += v.x; acc.y += v.y;
    }
    float di = dinv[i];
    float2 bv = ((const float2*)bias)[lane];
    float ox = acc.x * di + bv.x;
    float oy = acc.y * di + bv.y;
    if (RELU) { ox = fmaxf(ox, 0.f); oy = fmaxf(oy, 0.f); }
    ((float2*)hout)[(size_t)i * 64 + lane] = make_float2(ox, oy);
}

// ---------------- mean pool (fp32 h) ----------------

__global__ __launch_bounds__(128) void pool_kernel(const float* __restrict__ h,
                                                   const int* __restrict__ batch,
                                                   float* __restrict__ out, int N) {
    int g = blockIdx.x;
    int j = threadIdx.x;
    int lo = 0, hi = N;
    while (lo < hi) { int mid = (lo + hi) >> 1; if (batch[mid] < g) lo = mid + 1; else hi = mid; }
    int start = lo;
    hi = N;
    while (lo < hi) { int mid = (lo + hi) >> 1; if (batch[mid] < g + 1) lo = mid + 1; else hi = mid; }
    int end = lo;
    float acc = 0.f;
    for (int i = start; i < end; ++i) acc += h[(size_t)i * 128 + j];
    int cnt = end - start;
    out[(size_t)g * 128 + j] = acc / (float)max(cnt, 1);
}

// ---------------- driver ----------------

extern "C" void kernel_launch(void* const* d_in, const int* in_sizes, int n_in,
                              void* d_out, int out_size, void* d_ws, size_t ws_size,
                              hipStream_t stream) {
    const float* x     = (const float*)d_in[0];
    const int*   edge  = (const int*)d_in[1];
    const int*   batch = (const int*)d_in[2];
    const float* W1    = (const float*)d_in[3];
    const float* b1    = (const float*)d_in[4];
    const float* W2    = (const float*)d_in[5];
    const float* b2    = (const float*)d_in[6];
    const float* W3    = (const float*)d_in[7];
    const float* b3    = (const float*)d_in[8];
    float* out = (float*)d_out;

    const int N = in_sizes[2];
    const int E = in_sizes[1] / 2;
    const int G = out_size / 128;

    const int* src = edge;
    const int* dst = edge + E;

    char* base = (char*)d_ws;
    size_t off = 0;
    auto carve = [&](size_t bytes) -> char* {
        char* p = base + off;
        off = (off + bytes + 255) & ~(size_t)255;
        return p;
    };
    int*            rowptr     = (int*)carve((size_t)(N + 1) * 4);
    float*          dinv       = (float*)carve((size_t)N * 4);
    int*            csr        = (int*)carve((size_t)E * 4);
    int*            ebuf       = (int*)carve((size_t)E * 4);
    unsigned short* WT         = (unsigned short*)carve((size_t)4 * 16384 * 2);
    int*            bcount     = (int*)carve(256 * 4);
    int*            blockoff   = (int*)carve(260 * 4);
    int*            bucket_cur = (int*)carve(256 * 4);
    float*          ybuf       = (float*)carve((size_t)N * 26 * 4);
    float*          bufH       = (float*)carve((size_t)N * 128 * 4);
    unsigned short* bufS       = (unsigned short*)carve((size_t)N * 128 * 2);

    if (off > ws_size) {
        hipMemsetAsync(d_out, 0, (size_t)out_size * 4, stream);
        return;
    }

    const int NB   = (N + BKT_NODES - 1) / BKT_NODES;   // 196 (must be <= 256)
    const int EBK  = (E + EPB - 1) / EPB;               // 196

    hipMemsetAsync(bcount, 0, 256 * 4, stream);
    bucket_hist_kernel<<<EBK, 256, 0, stream>>>(dst, bcount, E);
    scan_buckets_kernel<<<1, 256, 0, stream>>>(bcount, blockoff, bucket_cur, NB);
    bucket_scatter_kernel<<<EBK, 256, 0, stream>>>(src, dst, bucket_cur, ebuf, E);
    bucket_csr_kernel<<<NB, 256, 0, stream>>>(ebuf, blockoff, rowptr, dinv, csr, N, NB);
    wsplit_kernel<<<128, 256, 0, stream>>>(W2, W3, WT);

    const unsigned short* WT2h = WT;
    const unsigned short* WT2l = WT + 16384;
    const unsigned short* WT3h = WT + 2 * 16384;
    const unsigned short* WT3l = WT + 3 * 16384;

    int mmbk = (N * 128 + 255) / 256;
    int mfbk = (N + 63) / 64;
    int agbk = (N + 3) / 4;

    // layer 1: aggregate in x-space, then h1 = relu(y@W1 + b1)
    aggx_kernel<<<agbk, 256, 0, stream>>>(x, dinv, rowptr, csr, ybuf, N);
    matmul1b_kernel<<<mmbk, 256, 0, stream>>>(ybuf, W1, b1, bufH, N);
    // layer 2
    mm_mfma_kernel<<<mfbk, 256, 0, stream>>>(bufH, WT2h, WT2l, dinv, bufS, N);
    aggregate_kernel<1><<<agbk, 256, 0, stream>>>(bufS, dinv, rowptr, csr, b2, bufH, N);
    // layer 3
    mm_mfma_kernel<<<mfbk, 256, 0, stream>>>(bufH, WT3h, WT3l, dinv, bufS, N);
    aggregate_kernel<0><<<agbk, 256, 0, stream>>>(bufS, dinv, rowptr, csr, b3, bufH, N);
    // pool
    pool_kernel<<<G, 128, 0, stream>>>(bufH, batch, out, N);
}

// Round 8
// 507.109 us; speedup vs baseline: 3.3960x; 1.1156x over previous
//
#include <hip/hip_runtime.h>
#include <hip/hip_bf16.h>

// GCN: 3x (h = relu( dinv .* Agg( dinv .* (h@W) ) + b)) then mean-pool by graph.
// CSR build: bucketed counting sort (line-granular writes).
// Layer 1: aggregate in 26-dim x-space (Agg commutes with @W1), then MFMA
// matmul K=26 padded to 32 (round-7 fix: naive matmul1b was 87us issue-bound).
// Layers 2/3: MFMA bf16 hi/lo split matmul (fp32-accurate), bf16 gather table.

typedef __attribute__((ext_vector_type(8))) __bf16 bf16x8;
typedef __attribute__((ext_vector_type(4))) float f32x4;

union BF8 { bf16x8 v; unsigned short u[8]; };

#define BKT_SHIFT 9
#define BKT_NODES 512
#define EPB 8192               // edges per block in bucket passes

__device__ inline unsigned short f2bf(float f) {
    union { float f; unsigned u; } x; x.f = f;
    unsigned r = (x.u + 0x7FFFu + ((x.u >> 16) & 1u)) >> 16;
    return (unsigned short)r;
}
__device__ inline float bf2f(unsigned short u) {
    union { float f; unsigned u; } x; x.u = ((unsigned)u) << 16;
    return x.f;
}
__device__ inline float2 ld2bf(const unsigned short* p, size_t pair_idx) {
    unsigned v = ((const unsigned*)p)[pair_idx];
    union { float f; unsigned u; } a, b;
    a.u = (v & 0xFFFFu) << 16;
    b.u = v & 0xFFFF0000u;
    return make_float2(a.f, b.f);
}

// ---------------- CSR build: bucketed counting sort ----------------

__global__ __launch_bounds__(256) void bucket_hist_kernel(const int* __restrict__ dst,
                                                          int* __restrict__ bcount, int E) {
    __shared__ int lh[256];
    int t = threadIdx.x;
    lh[t] = 0;
    __syncthreads();
    int base = blockIdx.x * EPB;
    for (int i = t; i < EPB; i += 256) {
        int e = base + i;
        if (e < E) atomicAdd(&lh[dst[e] >> BKT_SHIFT], 1);
    }
    __syncthreads();
    if (lh[t]) atomicAdd(&bcount[t], lh[t]);
}

__global__ __launch_bounds__(256) void scan_buckets_kernel(const int* __restrict__ bcount,
                                                           int* __restrict__ blockoff,
                                                           int* __restrict__ bucket_cur, int NB) {
    __shared__ int sd[256];
    int t = threadIdx.x;
    int v = (t < NB) ? bcount[t] : 0;
    sd[t] = v;
    __syncthreads();
#pragma unroll
    for (int o = 1; o < 256; o <<= 1) {
        int u = (t >= o) ? sd[t - o] : 0;
        __syncthreads();
        sd[t] += u;
        __syncthreads();
    }
    if (t < NB) { int ex = sd[t] - v; blockoff[t] = ex; bucket_cur[t] = ex; }
    if (t == 255) blockoff[NB] = sd[255];   // = E
}

// scatter edges into bucket-grouped ebuf; rec = src | ((dst&511)<<20)
__global__ __launch_bounds__(256) void bucket_scatter_kernel(const int* __restrict__ src,
                                                             const int* __restrict__ dst,
                                                             int* __restrict__ bucket_cur,
                                                             int* __restrict__ ebuf, int E) {
    __shared__ int lh[256];
    __shared__ int lb[256];
    int t = threadIdx.x;
    lh[t] = 0;
    __syncthreads();
    int base = blockIdx.x * EPB;
    for (int i = t; i < EPB; i += 256) {
        int e = base + i;
        if (e < E) atomicAdd(&lh[dst[e] >> BKT_SHIFT], 1);
    }
    __syncthreads();
    int n = lh[t];
    if (n) lb[t] = atomicAdd(&bucket_cur[t], n);
    lh[t] = 0;
    __syncthreads();
    for (int i = t; i < EPB; i += 256) {
        int e = base + i;
        if (e < E) {
            int d = dst[e];
            int k = d >> BKT_SHIFT;
            int r = atomicAdd(&lh[k], 1);
            ebuf[lb[k] + r] = src[e] | ((d & (BKT_NODES - 1)) << 20);
        }
    }
}

// per-bucket CSR finalize: node counts, rowptr, dinv, sorted csr (src ids)
__global__ __launch_bounds__(256) void bucket_csr_kernel(const int* __restrict__ ebuf,
                                                         const int* __restrict__ blockoff,
                                                         int* __restrict__ rowptr,
                                                         float* __restrict__ dinv,
                                                         int* __restrict__ csr, int N, int NB) {
    __shared__ int cnt[BKT_NODES];
    __shared__ int sd[256];
    int b = blockIdx.x, t = threadIdx.x;
    int node0 = b * BKT_NODES;
    int nn = min(BKT_NODES, N - node0);
    int ebase = blockoff[b];
    int ecnt = blockoff[b + 1] - ebase;
    cnt[t] = 0; cnt[t + 256] = 0;
    __syncthreads();
    for (int i = t; i < ecnt; i += 256)
        atomicAdd(&cnt[ebuf[ebase + i] >> 20], 1);
    __syncthreads();
    int c0 = cnt[2 * t], c1 = cnt[2 * t + 1];
    sd[t] = c0 + c1;
    __syncthreads();
#pragma unroll
    for (int o = 1; o < 256; o <<= 1) {
        int u = (t >= o) ? sd[t - o] : 0;
        __syncthreads();
        sd[t] += u;
        __syncthreads();
    }
    int ex = sd[t] - c0 - c1;                       // exclusive prefix for node 2t
    if (2 * t < nn) {
        rowptr[node0 + 2 * t] = ebase + ex;
        dinv[node0 + 2 * t]   = rsqrtf((float)c0 + 1.0f);
    }
    if (2 * t + 1 < nn) {
        rowptr[node0 + 2 * t + 1] = ebase + ex + c0;
        dinv[node0 + 2 * t + 1]   = rsqrtf((float)c1 + 1.0f);
    }
    if (b == NB - 1 && t == 0) rowptr[N] = ebase + ecnt;   // = E
    __syncthreads();            // all cnt reads done
    cnt[2 * t] = ex;            // reuse cnt as scatter cursor
    cnt[2 * t + 1] = ex + c0;
    __syncthreads();
    for (int i = t; i < ecnt; i += 256) {
        int rec = ebuf[ebase + i];
        int p = atomicAdd(&cnt[rec >> 20], 1);
        csr[ebase + p] = rec & 0xFFFFF;
    }
}

// ---------------- W transpose + hi/lo bf16 split ----------------
// WT tables (W2,W3): [which][hi/lo][col][k=128], each 128x128 ushort.

__global__ __launch_bounds__(256) void wsplit_kernel(const float* __restrict__ W2,
                                                     const float* __restrict__ W3,
                                                     unsigned short* __restrict__ WT) {
    int t = blockIdx.x * blockDim.x + threadIdx.x;   // 0 .. 32767
    int which = t >> 14;
    int idx = t & 16383;
    int k = idx >> 7, c = idx & 127;
    const float* W = which ? W3 : W2;
    float w = W[k * 128 + c];
    unsigned short hi = f2bf(w);
    unsigned short lo = f2bf(w - bf2f(hi));
    unsigned short* Th = WT + (size_t)which * 2 * 16384;
    unsigned short* Tl = Th + 16384;
    Th[c * 128 + k] = hi;
    Tl[c * 128 + k] = lo;
}

// W1T tables: [hi/lo][col=128][k=32], k>=26 zero-padded.
__global__ __launch_bounds__(256) void wsplit1_kernel(const float* __restrict__ W1,
                                                      unsigned short* __restrict__ W1T) {
    int t = blockIdx.x * blockDim.x + threadIdx.x;   // 0 .. 4095
    int c = t >> 5, k = t & 31;
    float w = (k < 26) ? W1[k * 128 + c] : 0.f;
    unsigned short hi = f2bf(w);
    unsigned short lo = f2bf(w - bf2f(hi));
    W1T[c * 32 + k]        = hi;
    W1T[4096 + c * 32 + k] = lo;
}

// ---------------- layer 1: aggregate in 26-dim x-space ----------------
// y[i] = dinv[i] * ( dinv[i]*x[i] + sum_{src->i} dinv[src]*x[src] )

__global__ __launch_bounds__(256) void aggx_kernel(const float* __restrict__ x,
                                                   const float* __restrict__ dinv,
                                                   const int* __restrict__ rowptr,
                                                   const int* __restrict__ csr,
                                                   float* __restrict__ y, int N) {
    int wid  = (int)((blockIdx.x * blockDim.x + threadIdx.x) >> 6);
    int lane = threadIdx.x & 63;
    if (wid >= N) return;
    const int i = wid;
    int start = __builtin_amdgcn_readfirstlane(rowptr[i]);
    int end   = __builtin_amdgcn_readfirstlane(rowptr[i + 1]);
    float di = dinv[i];
    float xv = (lane < 26) ? x[(size_t)i * 26 + lane] : 0.f;
    float acc = di * xv;
    int e = start;
    for (; e + 8 <= end; e += 8) {
        int idx[8];
#pragma unroll
        for (int j = 0; j < 8; ++j) idx[j] = csr[e + j];
#pragma unroll
        for (int j = 0; j < 8; ++j) {
            float v = (lane < 26) ? x[(size_t)idx[j] * 26 + lane] : 0.f;
            acc = fmaf(dinv[idx[j]], v, acc);
        }
    }
    for (; e < end; ++e) {
        int sn = csr[e];
        float v = (lane < 26) ? x[(size_t)sn * 26 + lane] : 0.f;
        acc = fmaf(dinv[sn], v, acc);
    }
    if (lane < 26) y[(size_t)i * 26 + lane] = acc * di;
}

// ---------------- layer-1 MFMA matmul: h = relu(y @ W1 + b1), K=26 pad 32 ----

__global__ __launch_bounds__(256) void mm1_mfma_kernel(const float* __restrict__ y,
                                                       const unsigned short* __restrict__ W1T,
                                                       const float* __restrict__ b1,
                                                       float* __restrict__ h, int N) {
    int wave = threadIdx.x >> 6;
    int lane = threadIdx.x & 63;
    int r0 = blockIdx.x * 64 + wave * 16;
    int arow = r0 + (lane & 15);
    int acl = min(arow, N - 1);
    int kgrp = lane >> 4;                       // 0..3; k = kgrp*8 + j
    const float* yrow = y + (size_t)acl * 26;

    BF8 ah, al;
#pragma unroll
    for (int j = 0; j < 8; ++j) {
        int k = kgrp * 8 + j;
        float v = (k < 26) ? yrow[k] : 0.f;
        unsigned short hb = f2bf(v);
        ah.u[j] = hb;
        al.u[j] = f2bf(v - bf2f(hb));
    }

    const unsigned short* bh_base = W1T + (size_t)(lane & 15) * 32 + kgrp * 8;
    const unsigned short* bl_base = bh_base + 4096;

    f32x4 acc[8];
#pragma unroll
    for (int i = 0; i < 8; ++i) acc[i] = f32x4{0.f, 0.f, 0.f, 0.f};

#pragma unroll
    for (int ct = 0; ct < 8; ++ct) {
        BF8 bh, bl;
        bh.v = *(const bf16x8*)(bh_base + (size_t)ct * 16 * 32);
        bl.v = *(const bf16x8*)(bl_base + (size_t)ct * 16 * 32);
        acc[ct] = __builtin_amdgcn_mfma_f32_16x16x32_bf16(ah.v, bh.v, acc[ct], 0, 0, 0);
        acc[ct] = __builtin_amdgcn_mfma_f32_16x16x32_bf16(al.v, bh.v, acc[ct], 0, 0, 0);
        acc[ct] = __builtin_amdgcn_mfma_f32_16x16x32_bf16(ah.v, bl.v, acc[ct], 0, 0, 0);
    }

    // C/D layout: col=lane&15, row=(lane>>4)*4+reg
    int rbase = r0 + (lane >> 4) * 4;
#pragma unroll
    for (int r = 0; r < 4; ++r) {
        int row = rbase + r;
        if (row < N) {
#pragma unroll
            for (int ct = 0; ct < 8; ++ct) {
                int col = ct * 16 + (lane & 15);
                h[(size_t)row * 128 + col] = fmaxf(acc[ct][r] + b1[col], 0.f);
            }
        }
    }
}

// ---------------- MFMA matmul: s = dinv * (h @ W), h fp32, s bf16 ------------

__global__ __launch_bounds__(256) void mm_mfma_kernel(const float* __restrict__ h,
                                                      const unsigned short* __restrict__ WTh,
                                                      const unsigned short* __restrict__ WTl,
                                                      const float* __restrict__ dinv,
                                                      unsigned short* __restrict__ s, int N) {
    int wave = threadIdx.x >> 6;
    int lane = threadIdx.x & 63;
    int r0 = blockIdx.x * 64 + wave * 16;
    int arow = r0 + (lane & 15);
    int acl = min(arow, N - 1);
    int kgrp = lane >> 4;                       // 0..3
    const float* hrow = h + (size_t)acl * 128 + kgrp * 8;

    f32x4 acc[8];
#pragma unroll
    for (int i = 0; i < 8; ++i) acc[i] = f32x4{0.f, 0.f, 0.f, 0.f};

    const unsigned short* bh_base = WTh + (size_t)(lane & 15) * 128 + kgrp * 8;
    const unsigned short* bl_base = WTl + (size_t)(lane & 15) * 128 + kgrp * 8;

#pragma unroll
    for (int ks = 0; ks < 4; ++ks) {
        const float4* p = (const float4*)(hrow + ks * 32);
        float4 v0 = p[0], v1 = p[1];
        float va[8] = {v0.x, v0.y, v0.z, v0.w, v1.x, v1.y, v1.z, v1.w};
        BF8 ah, al;
#pragma unroll
        for (int j = 0; j < 8; ++j) {
            unsigned short hb = f2bf(va[j]);
            ah.u[j] = hb;
            al.u[j] = f2bf(va[j] - bf2f(hb));
        }
#pragma unroll
        for (int ct = 0; ct < 8; ++ct) {
            BF8 bh, bl;
            bh.v = *(const bf16x8*)(bh_base + ks * 32 + (size_t)ct * 16 * 128);
            bl.v = *(const bf16x8*)(bl_base + ks * 32 + (size_t)ct * 16 * 128);
            acc[ct] = __builtin_amdgcn_mfma_f32_16x16x32_bf16(ah.v, bh.v, acc[ct], 0, 0, 0);
            acc[ct] = __builtin_amdgcn_mfma_f32_16x16x32_bf16(al.v, bh.v, acc[ct], 0, 0, 0);
            acc[ct] = __builtin_amdgcn_mfma_f32_16x16x32_bf16(ah.v, bl.v, acc[ct], 0, 0, 0);
        }
    }

    // C/D layout: col=lane&15, row=(lane>>4)*4+reg
    int rbase = r0 + (lane >> 4) * 4;
#pragma unroll
    for (int r = 0; r < 4; ++r) {
        int row = rbase + r;
        if (row < N) {
            float di = dinv[row];
#pragma unroll
            for (int ct = 0; ct < 8; ++ct) {
                int col = ct * 16 + (lane & 15);
                s[(size_t)row * 128 + col] = f2bf(acc[ct][r] * di);
            }
        }
    }
}

// ---------------- aggregation: one wave per node, bf16 gather ----------------

template <int RELU>
__global__ __launch_bounds__(256) void aggregate_kernel(const unsigned short* __restrict__ s,
                                                        const float* __restrict__ dinv,
                                                        const int* __restrict__ rowptr,
                                                        const int* __restrict__ csr,
                                                        const float* __restrict__ bias,
                                                        float* __restrict__ hout, int N) {
    int wid  = (int)((blockIdx.x * blockDim.x + threadIdx.x) >> 6);
    int lane = threadIdx.x & 63;
    if (wid >= N) return;
    const int i = wid;
    int start = __builtin_amdgcn_readfirstlane(rowptr[i]);
    int end   = __builtin_amdgcn_readfirstlane(rowptr[i + 1]);
    float2 acc = ld2bf(s, (size_t)i * 64 + lane);      // self-loop term
    int e = start;
    for (; e + 8 <= end; e += 8) {
        int idx[8];
#pragma unroll
        for (int j = 0; j < 8; ++j) idx[j] = csr[e + j];
#pragma unroll
        for (int j = 0; j < 8; ++j) {
            float2 v = ld2bf(s, (size_t)idx[j] * 64 + lane);
            acc.x += v.x; acc.y += v.y;
        }
    }
    for (; e < end; ++e) {
        int sn = csr[e];
        float2 v = ld2bf(s, (size_t)sn * 64 + lane);
        acc.x += v.x; acc.y += v.y;
    }
    float di = dinv[i];
    float2 bv = ((const float2*)bias)[lane];
    float ox = acc.x * di + bv.x;
    float oy = acc.y * di + bv.y;
    if (RELU) { ox = fmaxf(ox, 0.f); oy = fmaxf(oy, 0.f); }
    ((float2*)hout)[(size_t)i * 64 + lane] = make_float2(ox, oy);
}

// ---------------- mean pool (fp32 h) ----------------

__global__ __launch_bounds__(128) void pool_kernel(const float* __restrict__ h,
                                                   const int* __restrict__ batch,
                                                   float* __restrict__ out, int N) {
    int g = blockIdx.x;
    int j = threadIdx.x;
    int lo = 0, hi = N;
    while (lo < hi) { int mid = (lo + hi) >> 1; if (batch[mid] < g) lo = mid + 1; else hi = mid; }
    int start = lo;
    hi = N;
    while (lo < hi) { int mid = (lo + hi) >> 1; if (batch[mid] < g + 1) lo = mid + 1; else hi = mid; }
    int end = lo;
    float acc = 0.f;
    for (int i = start; i < end; ++i) acc += h[(size_t)i * 128 + j];
    int cnt = end - start;
    out[(size_t)g * 128 + j] = acc / (float)max(cnt, 1);
}

// ---------------- driver ----------------

extern "C" void kernel_launch(void* const* d_in, const int* in_sizes, int n_in,
                              void* d_out, int out_size, void* d_ws, size_t ws_size,
                              hipStream_t stream) {
    const float* x     = (const float*)d_in[0];
    const int*   edge  = (const int*)d_in[1];
    const int*   batch = (const int*)d_in[2];
    const float* W1    = (const float*)d_in[3];
    const float* b1    = (const float*)d_in[4];
    const float* W2    = (const float*)d_in[5];
    const float* b2    = (const float*)d_in[6];
    const float* W3    = (const float*)d_in[7];
    const float* b3    = (const float*)d_in[8];
    float* out = (float*)d_out;

    const int N = in_sizes[2];
    const int E = in_sizes[1] / 2;
    const int G = out_size / 128;

    const int* src = edge;
    const int* dst = edge + E;

    char* base = (char*)d_ws;
    size_t off = 0;
    auto carve = [&](size_t bytes) -> char* {
        char* p = base + off;
        off = (off + bytes + 255) & ~(size_t)255;
        return p;
    };
    int*            rowptr     = (int*)carve((size_t)(N + 1) * 4);
    float*          dinv       = (float*)carve((size_t)N * 4);
    int*            csr        = (int*)carve((size_t)E * 4);
    int*            ebuf       = (int*)carve((size_t)E * 4);
    unsigned short* WT         = (unsigned short*)carve((size_t)4 * 16384 * 2);
    unsigned short* W1T        = (unsigned short*)carve((size_t)2 * 4096 * 2);
    int*            bcount     = (int*)carve(256 * 4);
    int*            blockoff   = (int*)carve(260 * 4);
    int*            bucket_cur = (int*)carve(256 * 4);
    float*          ybuf       = (float*)carve((size_t)N * 26 * 4);
    float*          bufH       = (float*)carve((size_t)N * 128 * 4);
    unsigned short* bufS       = (unsigned short*)carve((size_t)N * 128 * 2);

    if (off > ws_size) {
        hipMemsetAsync(d_out, 0, (size_t)out_size * 4, stream);
        return;
    }

    const int NB   = (N + BKT_NODES - 1) / BKT_NODES;   // 196 (must be <= 256)
    const int EBK  = (E + EPB - 1) / EPB;               // 196

    hipMemsetAsync(bcount, 0, 256 * 4, stream);
    bucket_hist_kernel<<<EBK, 256, 0, stream>>>(dst, bcount, E);
    scan_buckets_kernel<<<1, 256, 0, stream>>>(bcount, blockoff, bucket_cur, NB);
    bucket_scatter_kernel<<<EBK, 256, 0, stream>>>(src, dst, bucket_cur, ebuf, E);
    bucket_csr_kernel<<<NB, 256, 0, stream>>>(ebuf, blockoff, rowptr, dinv, csr, N, NB);
    wsplit_kernel<<<128, 256, 0, stream>>>(W2, W3, WT);
    wsplit1_kernel<<<16, 256, 0, stream>>>(W1, W1T);

    const unsigned short* WT2h = WT;
    const unsigned short* WT2l = WT + 16384;
    const unsigned short* WT3h = WT + 2 * 16384;
    const unsigned short* WT3l = WT + 3 * 16384;

    int mfbk = (N + 63) / 64;
    int agbk = (N + 3) / 4;

    // layer 1: aggregate in x-space, then h1 = relu(y@W1 + b1) via MFMA
    aggx_kernel<<<agbk, 256, 0, stream>>>(x, dinv, rowptr, csr, ybuf, N);
    mm1_mfma_kernel<<<mfbk, 256, 0, stream>>>(ybuf, W1T, b1, bufH, N);
    // layer 2
    mm_mfma_kernel<<<mfbk, 256, 0, stream>>>(bufH, WT2h, WT2l, dinv, bufS, N);
    aggregate_kernel<1><<<agbk, 256, 0, stream>>>(bufS, dinv, rowptr, csr, b2, bufH, N);
    // layer 3
    mm_mfma_kernel<<<mfbk, 256, 0, stream>>>(bufH, WT3h, WT3l, dinv, bufS, N);
    aggregate_kernel<0><<<agbk, 256, 0, stream>>>(bufS, dinv, rowptr, csr, b3, bufH, N);
    // pool
    pool_kernel<<<G, 128, 0, stream>>>(bufH, batch, out, N);
}

// Round 10
// 495.414 us; speedup vs baseline: 3.4762x; 1.0236x over previous
//
#include <hip/hip_runtime.h>
#include <hip/hip_bf16.h>

// GCN: 3x (h = relu( dinv .* Agg( dinv .* (h@W) ) + b)) then mean-pool by graph.
// CSR build: bucketed counting sort (line-granular writes).
// Layer 1: aggregate in padded 32-dim x-space (8 rows/iter, 16B/lane), MFMA matmul.
// Layers 2/3: MFMA bf16 hi/lo split matmul; aggregate gathers 4 rows/iter
// (16B/lane dwordx4, butterfly reduce) -- round-8 fix for latency-bound gather.

typedef __attribute__((ext_vector_type(8))) __bf16 bf16x8;
typedef __attribute__((ext_vector_type(4))) float f32x4;

union BF8 { bf16x8 v; unsigned short u[8]; };

#define BKT_SHIFT 9
#define BKT_NODES 512
#define EPB 8192               // edges per block in bucket passes

__device__ inline unsigned short f2bf(float f) {
    union { float f; unsigned u; } x; x.f = f;
    unsigned r = (x.u + 0x7FFFu + ((x.u >> 16) & 1u)) >> 16;
    return (unsigned short)r;
}
__device__ inline float bf2f(unsigned short u) {
    union { float f; unsigned u; } x; x.u = ((unsigned)u) << 16;
    return x.f;
}
__device__ inline float bflo(unsigned v) {
    union { float f; unsigned u; } x; x.u = (v & 0xFFFFu) << 16; return x.f;
}
__device__ inline float bfhi(unsigned v) {
    union { float f; unsigned u; } x; x.u = v & 0xFFFF0000u; return x.f;
}

// ---------------- CSR build: bucketed counting sort ----------------

__global__ __launch_bounds__(256) void bucket_hist_kernel(const int* __restrict__ dst,
                                                          int* __restrict__ bcount, int E) {
    __shared__ int lh[256];
    int t = threadIdx.x;
    lh[t] = 0;
    __syncthreads();
    int base = blockIdx.x * EPB;
    for (int i = t; i < EPB; i += 256) {
        int e = base + i;
        if (e < E) atomicAdd(&lh[dst[e] >> BKT_SHIFT], 1);
    }
    __syncthreads();
    if (lh[t]) atomicAdd(&bcount[t], lh[t]);
}

__global__ __launch_bounds__(256) void scan_buckets_kernel(const int* __restrict__ bcount,
                                                           int* __restrict__ blockoff,
                                                           int* __restrict__ bucket_cur, int NB) {
    __shared__ int sd[256];
    int t = threadIdx.x;
    int v = (t < NB) ? bcount[t] : 0;
    sd[t] = v;
    __syncthreads();
#pragma unroll
    for (int o = 1; o < 256; o <<= 1) {
        int u = (t >= o) ? sd[t - o] : 0;
        __syncthreads();
        sd[t] += u;
        __syncthreads();
    }
    if (t < NB) { int ex = sd[t] - v; blockoff[t] = ex; bucket_cur[t] = ex; }
    if (t == 255) blockoff[NB] = sd[255];   // = E
}

// scatter edges into bucket-grouped ebuf; rec = src | ((dst&511)<<20)
__global__ __launch_bounds__(256) void bucket_scatter_kernel(const int* __restrict__ src,
                                                             const int* __restrict__ dst,
                                                             int* __restrict__ bucket_cur,
                                                             int* __restrict__ ebuf, int E) {
    __shared__ int lh[256];
    __shared__ int lb[256];
    int t = threadIdx.x;
    lh[t] = 0;
    __syncthreads();
    int base = blockIdx.x * EPB;
    for (int i = t; i < EPB; i += 256) {
        int e = base + i;
        if (e < E) atomicAdd(&lh[dst[e] >> BKT_SHIFT], 1);
    }
    __syncthreads();
    int n = lh[t];
    if (n) lb[t] = atomicAdd(&bucket_cur[t], n);
    lh[t] = 0;
    __syncthreads();
    for (int i = t; i < EPB; i += 256) {
        int e = base + i;
        if (e < E) {
            int d = dst[e];
            int k = d >> BKT_SHIFT;
            int r = atomicAdd(&lh[k], 1);
            ebuf[lb[k] + r] = src[e] | ((d & (BKT_NODES - 1)) << 20);
        }
    }
}

// per-bucket CSR finalize: node counts, rowptr, dinv, sorted csr (src ids)
__global__ __launch_bounds__(256) void bucket_csr_kernel(const int* __restrict__ ebuf,
                                                         const int* __restrict__ blockoff,
                                                         int* __restrict__ rowptr,
                                                         float* __restrict__ dinv,
                                                         int* __restrict__ csr, int N, int NB) {
    __shared__ int cnt[BKT_NODES];
    __shared__ int sd[256];
    int b = blockIdx.x, t = threadIdx.x;
    int node0 = b * BKT_NODES;
    int nn = min(BKT_NODES, N - node0);
    int ebase = blockoff[b];
    int ecnt = blockoff[b + 1] - ebase;
    cnt[t] = 0; cnt[t + 256] = 0;
    __syncthreads();
    for (int i = t; i < ecnt; i += 256)
        atomicAdd(&cnt[ebuf[ebase + i] >> 20], 1);
    __syncthreads();
    int c0 = cnt[2 * t], c1 = cnt[2 * t + 1];
    sd[t] = c0 + c1;
    __syncthreads();
#pragma unroll
    for (int o = 1; o < 256; o <<= 1) {
        int u = (t >= o) ? sd[t - o] : 0;
        __syncthreads();
        sd[t] += u;
        __syncthreads();
    }
    int ex = sd[t] - c0 - c1;                       // exclusive prefix for node 2t
    if (2 * t < nn) {
        rowptr[node0 + 2 * t] = ebase + ex;
        dinv[node0 + 2 * t]   = rsqrtf((float)c0 + 1.0f);
    }
    if (2 * t + 1 < nn) {
        rowptr[node0 + 2 * t + 1] = ebase + ex + c0;
        dinv[node0 + 2 * t + 1]   = rsqrtf((float)c1 + 1.0f);
    }
    if (b == NB - 1 && t == 0) rowptr[N] = ebase + ecnt;   // = E
    __syncthreads();            // all cnt reads done
    cnt[2 * t] = ex;            // reuse cnt as scatter cursor
    cnt[2 * t + 1] = ex + c0;
    __syncthreads();
    for (int i = t; i < ecnt; i += 256) {
        int rec = ebuf[ebase + i];
        int p = atomicAdd(&cnt[rec >> 20], 1);
        csr[ebase + p] = rec & 0xFFFFF;
    }
}

// ---------------- W transpose + hi/lo bf16 split ----------------

__global__ __launch_bounds__(256) void wsplit_kernel(const float* __restrict__ W2,
                                                     const float* __restrict__ W3,
                                                     unsigned short* __restrict__ WT) {
    int t = blockIdx.x * blockDim.x + threadIdx.x;   // 0 .. 32767
    int which = t >> 14;
    int idx = t & 16383;
    int k = idx >> 7, c = idx & 127;
    const float* W = which ? W3 : W2;
    float w = W[k * 128 + c];
    unsigned short hi = f2bf(w);
    unsigned short lo = f2bf(w - bf2f(hi));
    unsigned short* Th = WT + (size_t)which * 2 * 16384;
    unsigned short* Tl = Th + 16384;
    Th[c * 128 + k] = hi;
    Tl[c * 128 + k] = lo;
}

// W1T tables: [hi/lo][col=128][k=32], k>=26 zero-padded.
__global__ __launch_bounds__(256) void wsplit1_kernel(const float* __restrict__ W1,
                                                      unsigned short* __restrict__ W1T) {
    int t = blockIdx.x * blockDim.x + threadIdx.x;   // 0 .. 4095
    int c = t >> 5, k = t & 31;
    float w = (k < 26) ? W1[k * 128 + c] : 0.f;
    unsigned short hi = f2bf(w);
    unsigned short lo = f2bf(w - bf2f(hi));
    W1T[c * 32 + k]        = hi;
    W1T[4096 + c * 32 + k] = lo;
}

// ---------------- x pad: xp[N][32] fp32, k>=26 zeroed ----------------

__global__ __launch_bounds__(256) void xpad_kernel(const float* __restrict__ x,
                                                   float* __restrict__ xp, int N) {
    int t = blockIdx.x * blockDim.x + threadIdx.x;
    if (t >= N * 32) return;
    int i = t >> 5, k = t & 31;
    xp[t] = (k < 26) ? x[(size_t)i * 26 + k] : 0.f;
}

// ---------------- layer 1 aggregate: 8 rows/iter, 16B/lane ----------------
// y[i] = dinv[i] * ( dinv[i]*x[i] + sum_{src->i} dinv[src]*x[src] ), 32-dim padded

__global__ __launch_bounds__(256) void aggx8_kernel(const float* __restrict__ xp,
                                                    const float* __restrict__ dinv,
                                                    const int* __restrict__ rowptr,
                                                    const int* __restrict__ csr,
                                                    float* __restrict__ yp, int N) {
    int wid  = (int)((blockIdx.x * blockDim.x + threadIdx.x) >> 6);
    int lane = threadIdx.x & 63;
    if (wid >= N) return;
    const int i = wid;
    int start = __builtin_amdgcn_readfirstlane(rowptr[i]);
    int end   = __builtin_amdgcn_readfirstlane(rowptr[i + 1]);
    int grp = lane >> 3;        // 0..7 : edge slot
    int fl  = lane & 7;         // features fl*4 .. fl*4+3

    float4 acc = make_float4(0.f, 0.f, 0.f, 0.f);
    int e = start;
    for (; e + 8 <= end; e += 8) {
        int ci = csr[e + grp];                       // 8 distinct addrs, broadcast in-group
        float dv = dinv[ci];
        float4 v = *(const float4*)(xp + (size_t)ci * 32 + fl * 4);
        acc.x = fmaf(dv, v.x, acc.x); acc.y = fmaf(dv, v.y, acc.y);
        acc.z = fmaf(dv, v.z, acc.z); acc.w = fmaf(dv, v.w, acc.w);
    }
    if (e < end) {
        int e0 = e + grp;
        if (e0 < end) {
            int ci = csr[e0];
            float dv = dinv[ci];
            float4 v = *(const float4*)(xp + (size_t)ci * 32 + fl * 4);
            acc.x = fmaf(dv, v.x, acc.x); acc.y = fmaf(dv, v.y, acc.y);
            acc.z = fmaf(dv, v.z, acc.z); acc.w = fmaf(dv, v.w, acc.w);
        }
    }
    // butterfly-reduce across the 8 groups
#pragma unroll
    for (int off = 8; off <= 32; off <<= 1) {
        acc.x += __shfl_xor(acc.x, off);
        acc.y += __shfl_xor(acc.y, off);
        acc.z += __shfl_xor(acc.z, off);
        acc.w += __shfl_xor(acc.w, off);
    }
    float di = dinv[i];
    float4 xv = *(const float4*)(xp + (size_t)i * 32 + fl * 4);
    acc.x = fmaf(di, xv.x, acc.x); acc.y = fmaf(di, xv.y, acc.y);
    acc.z = fmaf(di, xv.z, acc.z); acc.w = fmaf(di, xv.w, acc.w);
    if (grp == 0) {
        float4 o = make_float4(acc.x * di, acc.y * di, acc.z * di, acc.w * di);
        *(float4*)(yp + (size_t)i * 32 + fl * 4) = o;
    }
}

// ---------------- layer-1 MFMA matmul: h = relu(yp @ W1 + b1), K=32 ----------

__global__ __launch_bounds__(256) void mm1_mfma_kernel(const float* __restrict__ yp,
                                                       const unsigned short* __restrict__ W1T,
                                                       const float* __restrict__ b1,
                                                       float* __restrict__ h, int N) {
    int wave = threadIdx.x >> 6;
    int lane = threadIdx.x & 63;
    int r0 = blockIdx.x * 64 + wave * 16;
    int arow = r0 + (lane & 15);
    int acl = min(arow, N - 1);
    int kgrp = lane >> 4;                       // 0..3; k = kgrp*8 + j
    const float* yrow = yp + (size_t)acl * 32 + kgrp * 8;

    float4 v0 = ((const float4*)yrow)[0];
    float4 v1 = ((const float4*)yrow)[1];
    float va[8] = {v0.x, v0.y, v0.z, v0.w, v1.x, v1.y, v1.z, v1.w};
    BF8 ah, al;
#pragma unroll
    for (int j = 0; j < 8; ++j) {
        unsigned short hb = f2bf(va[j]);
        ah.u[j] = hb;
        al.u[j] = f2bf(va[j] - bf2f(hb));
    }

    const unsigned short* bh_base = W1T + (size_t)(lane & 15) * 32 + kgrp * 8;
    const unsigned short* bl_base = bh_base + 4096;

    f32x4 acc[8];
#pragma unroll
    for (int i = 0; i < 8; ++i) acc[i] = f32x4{0.f, 0.f, 0.f, 0.f};

#pragma unroll
    for (int ct = 0; ct < 8; ++ct) {
        BF8 bh, bl;
        bh.v = *(const bf16x8*)(bh_base + (size_t)ct * 16 * 32);
        bl.v = *(const bf16x8*)(bl_base + (size_t)ct * 16 * 32);
        acc[ct] = __builtin_amdgcn_mfma_f32_16x16x32_bf16(ah.v, bh.v, acc[ct], 0, 0, 0);
        acc[ct] = __builtin_amdgcn_mfma_f32_16x16x32_bf16(al.v, bh.v, acc[ct], 0, 0, 0);
        acc[ct] = __builtin_amdgcn_mfma_f32_16x16x32_bf16(ah.v, bl.v, acc[ct], 0, 0, 0);
    }

    int rbase = r0 + (lane >> 4) * 4;
#pragma unroll
    for (int r = 0; r < 4; ++r) {
        int row = rbase + r;
        if (row < N) {
#pragma unroll
            for (int ct = 0; ct < 8; ++ct) {
                int col = ct * 16 + (lane & 15);
                h[(size_t)row * 128 + col] = fmaxf(acc[ct][r] + b1[col], 0.f);
            }
        }
    }
}

// ---------------- MFMA matmul: s = dinv * (h @ W), h fp32, s bf16 ------------

__global__ __launch_bounds__(256) void mm_mfma_kernel(const float* __restrict__ h,
                                                      const unsigned short* __restrict__ WTh,
                                                      const unsigned short* __restrict__ WTl,
                                                      const float* __restrict__ dinv,
                                                      unsigned short* __restrict__ s, int N) {
    int wave = threadIdx.x >> 6;
    int lane = threadIdx.x & 63;
    int r0 = blockIdx.x * 64 + wave * 16;
    int arow = r0 + (lane & 15);
    int acl = min(arow, N - 1);
    int kgrp = lane >> 4;                       // 0..3
    const float* hrow = h + (size_t)acl * 128 + kgrp * 8;

    f32x4 acc[8];
#pragma unroll
    for (int i = 0; i < 8; ++i) acc[i] = f32x4{0.f, 0.f, 0.f, 0.f};

    const unsigned short* bh_base = WTh + (size_t)(lane & 15) * 128 + kgrp * 8;
    const unsigned short* bl_base = WTl + (size_t)(lane & 15) * 128 + kgrp * 8;

#pragma unroll
    for (int ks = 0; ks < 4; ++ks) {
        const float4* p = (const float4*)(hrow + ks * 32);
        float4 v0 = p[0], v1 = p[1];
        float va[8] = {v0.x, v0.y, v0.z, v0.w, v1.x, v1.y, v1.z, v1.w};
        BF8 ah, al;
#pragma unroll
        for (int j = 0; j < 8; ++j) {
            unsigned short hb = f2bf(va[j]);
            ah.u[j] = hb;
            al.u[j] = f2bf(va[j] - bf2f(hb));
        }
#pragma unroll
        for (int ct = 0; ct < 8; ++ct) {
            BF8 bh, bl;
            bh.v = *(const bf16x8*)(bh_base + ks * 32 + (size_t)ct * 16 * 128);
            bl.v = *(const bf16x8*)(bl_base + ks * 32 + (size_t)ct * 16 * 128);
            acc[ct] = __builtin_amdgcn_mfma_f32_16x16x32_bf16(ah.v, bh.v, acc[ct], 0, 0, 0);
            acc[ct] = __builtin_amdgcn_mfma_f32_16x16x32_bf16(al.v, bh.v, acc[ct], 0, 0, 0);
            acc[ct] = __builtin_amdgcn_mfma_f32_16x16x32_bf16(ah.v, bl.v, acc[ct], 0, 0, 0);
        }
    }

    int rbase = r0 + (lane >> 4) * 4;
#pragma unroll
    for (int r = 0; r < 4; ++r) {
        int row = rbase + r;
        if (row < N) {
            float di = dinv[row];
#pragma unroll
            for (int ct = 0; ct < 8; ++ct) {
                int col = ct * 16 + (lane & 15);
                s[(size_t)row * 128 + col] = f2bf(acc[ct][r] * di);
            }
        }
    }
}

// ------------- aggregation: 4 rows/iter, 16B/lane, butterfly reduce ---------

template <int RELU>
__global__ __launch_bounds__(256) void aggregate4_kernel(const unsigned short* __restrict__ s,
                                                         const float* __restrict__ dinv,
                                                         const int* __restrict__ rowptr,
                                                         const int* __restrict__ csr,
                                                         const float* __restrict__ bias,
                                                         float* __restrict__ hout, int N) {
    int wid  = (int)((blockIdx.x * blockDim.x + threadIdx.x) >> 6);
    int lane = threadIdx.x & 63;
    if (wid >= N) return;
    const int i = wid;
    int start = __builtin_amdgcn_readfirstlane(rowptr[i]);
    int end   = __builtin_amdgcn_readfirstlane(rowptr[i + 1]);
    int grp = lane >> 4;        // 0..3 : edge slot
    int fl  = lane & 15;        // features fl*8 .. fl*8+7

    float acc[8];
#pragma unroll
    for (int j = 0; j < 8; ++j) acc[j] = 0.f;

    int e = start;
    for (; e + 8 <= end; e += 8) {
        int ci0 = csr[e + grp];
        int ci1 = csr[e + 4 + grp];
        uint4 w0 = *(const uint4*)(s + (size_t)ci0 * 128 + fl * 8);
        uint4 w1 = *(const uint4*)(s + (size_t)ci1 * 128 + fl * 8);
        acc[0] += bflo(w0.x); acc[1] += bfhi(w0.x);
        acc[2] += bflo(w0.y); acc[3] += bfhi(w0.y);
        acc[4] += bflo(w0.z); acc[5] += bfhi(w0.z);
        acc[6] += bflo(w0.w); acc[7] += bfhi(w0.w);
        acc[0] += bflo(w1.x); acc[1] += bfhi(w1.x);
        acc[2] += bflo(w1.y); acc[3] += bfhi(w1.y);
        acc[4] += bflo(w1.z); acc[5] += bfhi(w1.z);
        acc[6] += bflo(w1.w); acc[7] += bfhi(w1.w);
    }
    if (e < end) {
        int e0 = e + grp, e1 = e + 4 + grp;
        if (e0 < end) {
            int ci = csr[e0];
            uint4 w = *(const uint4*)(s + (size_t)ci * 128 + fl * 8);
            acc[0] += bflo(w.x); acc[1] += bfhi(w.x);
            acc[2] += bflo(w.y); acc[3] += bfhi(w.y);
            acc[4] += bflo(w.z); acc[5] += bfhi(w.z);
            acc[6] += bflo(w.w); acc[7] += bfhi(w.w);
        }
        if (e1 < end) {
            int ci = csr[e1];
            uint4 w = *(const uint4*)(s + (size_t)ci * 128 + fl * 8);
            acc[0] += bflo(w.x); acc[1] += bfhi(w.x);
            acc[2] += bflo(w.y); acc[3] += bfhi(w.y);
            acc[4] += bflo(w.z); acc[5] += bfhi(w.z);
            acc[6] += bflo(w.w); acc[7] += bfhi(w.w);
        }
    }
    // reduce across the 4 edge-slot groups
#pragma unroll
    for (int off = 16; off <= 32; off <<= 1) {
#pragma unroll
        for (int j = 0; j < 8; ++j) acc[j] += __shfl_xor(acc[j], off);
    }
    // self-loop term
    {
        uint4 w = *(const uint4*)(s + (size_t)i * 128 + fl * 8);
        acc[0] += bflo(w.x); acc[1] += bfhi(w.x);
        acc[2] += bflo(w.y); acc[3] += bfhi(w.y);
        acc[4] += bflo(w.z); acc[5] += bfhi(w.z);
        acc[6] += bflo(w.w); acc[7] += bfhi(w.w);
    }
    float di = dinv[i];
    int j0 = grp * 2;                           // this lane writes features fl*8 + j0, +1
    int f = fl * 8 + j0;
    const float2 bv = ((const float2*)bias)[f >> 1];
    float ox = acc[j0] * di + bv.x;
    float oy = acc[j0 + 1] * di + bv.y;
    if (RELU) { ox = fmaxf(ox, 0.f); oy = fmaxf(oy, 0.f); }
    ((float2*)hout)[(size_t)i * 64 + (f >> 1)] = make_float2(ox, oy);
}

// ---------------- mean pool (fp32 h) ----------------

__global__ __launch_bounds__(128) void pool_kernel(const float* __restrict__ h,
                                                   const int* __restrict__ batch,
                                                   float* __restrict__ out, int N) {
    int g = blockIdx.x;
    int j = threadIdx.x;
    int lo = 0, hi = N;
    while (lo < hi) { int mid = (lo + hi) >> 1; if (batch[mid] < g) lo = mid + 1; else hi = mid; }
    int start = lo;
    hi = N;
    while (lo < hi) { int mid = (lo + hi) >> 1; if (batch[mid] < g + 1) lo = mid + 1; else hi = mid; }
    int end = lo;
    float acc = 0.f;
    for (int i = start; i < end; ++i) acc += h[(size_t)i * 128 + j];
    int cnt = end - start;
    out[(size_t)g * 128 + j] = acc / (float)max(cnt, 1);
}

// ---------------- driver ----------------

extern "C" void kernel_launch(void* const* d_in, const int* in_sizes, int n_in,
                              void* d_out, int out_size, void* d_ws, size_t ws_size,
                              hipStream_t stream) {
    const float* x     = (const float*)d_in[0];
    const int*   edge  = (const int*)d_in[1];
    const int*   batch = (const int*)d_in[2];
    const float* W1    = (const float*)d_in[3];
    const float* b1    = (const float*)d_in[4];
    const float* W2    = (const float*)d_in[5];
    const float* b2    = (const float*)d_in[6];
    const float* W3    = (const float*)d_in[7];
    const float* b3    = (const float*)d_in[8];
    float* out = (float*)d_out;

    const int N = in_sizes[2];
    const int E = in_sizes[1] / 2;
    const int G = out_size / 128;

    const int* src = edge;
    const int* dst = edge + E;

    char* base = (char*)d_ws;
    size_t off = 0;
    auto carve = [&](size_t bytes) -> char* {
        char* p = base + off;
        off = (off + bytes + 255) & ~(size_t)255;
        return p;
    };
    int*            rowptr     = (int*)carve((size_t)(N + 1) * 4);
    float*          dinv       = (float*)carve((size_t)N * 4);
    int*            csr        = (int*)carve((size_t)E * 4);
    int*            ebuf       = (int*)carve((size_t)E * 4);
    unsigned short* WT         = (unsigned short*)carve((size_t)4 * 16384 * 2);
    unsigned short* W1T        = (unsigned short*)carve((size_t)2 * 4096 * 2);
    int*            bcount     = (int*)carve(256 * 4);
    int*            blockoff   = (int*)carve(260 * 4);
    int*            bucket_cur = (int*)carve(256 * 4);
    float*          xp         = (float*)carve((size_t)N * 32 * 4);
    float*          yp         = (float*)carve((size_t)N * 32 * 4);
    float*          bufH       = (float*)carve((size_t)N * 128 * 4);
    unsigned short* bufS       = (unsigned short*)carve((size_t)N * 128 * 2);

    if (off > ws_size) {
        hipMemsetAsync(d_out, 0, (size_t)out_size * 4, stream);
        return;
    }

    const int NB   = (N + BKT_NODES - 1) / BKT_NODES;   // 196 (must be <= 256)
    const int EBK  = (E + EPB - 1) / EPB;               // 196

    hipMemsetAsync(bcount, 0, 256 * 4, stream);
    bucket_hist_kernel<<<EBK, 256, 0, stream>>>(dst, bcount, E);
    scan_buckets_kernel<<<1, 256, 0, stream>>>(bcount, blockoff, bucket_cur, NB);
    bucket_scatter_kernel<<<EBK, 256, 0, stream>>>(src, dst, bucket_cur, ebuf, E);
    bucket_csr_kernel<<<NB, 256, 0, stream>>>(ebuf, blockoff, rowptr, dinv, csr, N, NB);
    wsplit_kernel<<<128, 256, 0, stream>>>(W2, W3, WT);
    wsplit1_kernel<<<16, 256, 0, stream>>>(W1, W1T);
    xpad_kernel<<<(N * 32 + 255) / 256, 256, 0, stream>>>(x, xp, N);

    const unsigned short* WT2h = WT;
    const unsigned short* WT2l = WT + 16384;
    const unsigned short* WT3h = WT + 2 * 16384;
    const unsigned short* WT3l = WT + 3 * 16384;

    int mfbk = (N + 63) / 64;
    int agbk = (N + 3) / 4;

    // layer 1: aggregate in padded x-space, then h1 = relu(y@W1 + b1) via MFMA
    aggx8_kernel<<<agbk, 256, 0, stream>>>(xp, dinv, rowptr, csr, yp, N);
    mm1_mfma_kernel<<<mfbk, 256, 0, stream>>>(yp, W1T, b1, bufH, N);
    // layer 2
    mm_mfma_kernel<<<mfbk, 256, 0, stream>>>(bufH, WT2h, WT2l, dinv, bufS, N);
    aggregate4_kernel<1><<<agbk, 256, 0, stream>>>(bufS, dinv, rowptr, csr, b2, bufH, N);
    // layer 3
    mm_mfma_kernel<<<mfbk, 256, 0, stream>>>(bufH, WT3h, WT3l, dinv, bufS, N);
    aggregate4_kernel<0><<<agbk, 256, 0, stream>>>(bufS, dinv, rowptr, csr, b3, bufH, N);
    // pool
    pool_kernel<<<G, 128, 0, stream>>>(bufH, batch, out, N);
}

// Round 12
// 426.465 us; speedup vs baseline: 4.0382x; 1.1617x over previous
//
#include <hip/hip_runtime.h>
#include <hip/hip_bf16.h>

// GCN: 3x (h = relu( dinv .* Agg( dinv .* (h@W) ) + b)) then mean-pool by graph.
// CSR build: bucketed counting sort (line-granular writes).
// Layer 1: aggregate in padded 32-dim x-space, MFMA matmul (K=32).
// Layers 2/3: MFMA bf16 hi/lo split matmul with B staged in LDS (round-10 fix:
// 64KB B-tables thrashed 32KB L1 -> latency-bound 71us, MfmaUtil 5%). 2-phase
// K-split (32KB LDS/phase), 16B-chunk XOR swizzle for uniform bank slots.
// Aggregate: 4 rows/iter 16B/lane gather (traffic-floor bound, ~65us).

typedef __attribute__((ext_vector_type(8))) __bf16 bf16x8;
typedef __attribute__((ext_vector_type(4))) float f32x4;

union BF8 { bf16x8 v; unsigned short u[8]; };

#define BKT_SHIFT 9
#define BKT_NODES 512
#define EPB 8192               // edges per block in bucket passes

__device__ inline unsigned short f2bf(float f) {
    union { float f; unsigned u; } x; x.f = f;
    unsigned r = (x.u + 0x7FFFu + ((x.u >> 16) & 1u)) >> 16;
    return (unsigned short)r;
}
__device__ inline float bf2f(unsigned short u) {
    union { float f; unsigned u; } x; x.u = ((unsigned)u) << 16;
    return x.f;
}
__device__ inline float bflo(unsigned v) {
    union { float f; unsigned u; } x; x.u = (v & 0xFFFFu) << 16; return x.f;
}
__device__ inline float bfhi(unsigned v) {
    union { float f; unsigned u; } x; x.u = v & 0xFFFF0000u; return x.f;
}

// ---------------- CSR build: bucketed counting sort ----------------

__global__ __launch_bounds__(256) void bucket_hist_kernel(const int* __restrict__ dst,
                                                          int* __restrict__ bcount, int E) {
    __shared__ int lh[256];
    int t = threadIdx.x;
    lh[t] = 0;
    __syncthreads();
    int base = blockIdx.x * EPB;
    for (int i = t; i < EPB; i += 256) {
        int e = base + i;
        if (e < E) atomicAdd(&lh[dst[e] >> BKT_SHIFT], 1);
    }
    __syncthreads();
    if (lh[t]) atomicAdd(&bcount[t], lh[t]);
}

__global__ __launch_bounds__(256) void scan_buckets_kernel(const int* __restrict__ bcount,
                                                           int* __restrict__ blockoff,
                                                           int* __restrict__ bucket_cur, int NB) {
    __shared__ int sd[256];
    int t = threadIdx.x;
    int v = (t < NB) ? bcount[t] : 0;
    sd[t] = v;
    __syncthreads();
#pragma unroll
    for (int o = 1; o < 256; o <<= 1) {
        int u = (t >= o) ? sd[t - o] : 0;
        __syncthreads();
        sd[t] += u;
        __syncthreads();
    }
    if (t < NB) { int ex = sd[t] - v; blockoff[t] = ex; bucket_cur[t] = ex; }
    if (t == 255) blockoff[NB] = sd[255];   // = E
}

// scatter edges into bucket-grouped ebuf; rec = src | ((dst&511)<<20)
__global__ __launch_bounds__(256) void bucket_scatter_kernel(const int* __restrict__ src,
                                                             const int* __restrict__ dst,
                                                             int* __restrict__ bucket_cur,
                                                             int* __restrict__ ebuf, int E) {
    __shared__ int lh[256];
    __shared__ int lb[256];
    int t = threadIdx.x;
    lh[t] = 0;
    __syncthreads();
    int base = blockIdx.x * EPB;
    for (int i = t; i < EPB; i += 256) {
        int e = base + i;
        if (e < E) atomicAdd(&lh[dst[e] >> BKT_SHIFT], 1);
    }
    __syncthreads();
    int n = lh[t];
    if (n) lb[t] = atomicAdd(&bucket_cur[t], n);
    lh[t] = 0;
    __syncthreads();
    for (int i = t; i < EPB; i += 256) {
        int e = base + i;
        if (e < E) {
            int d = dst[e];
            int k = d >> BKT_SHIFT;
            int r = atomicAdd(&lh[k], 1);
            ebuf[lb[k] + r] = src[e] | ((d & (BKT_NODES - 1)) << 20);
        }
    }
}

// per-bucket CSR finalize: node counts, rowptr, dinv, sorted csr (src ids)
__global__ __launch_bounds__(256) void bucket_csr_kernel(const int* __restrict__ ebuf,
                                                         const int* __restrict__ blockoff,
                                                         int* __restrict__ rowptr,
                                                         float* __restrict__ dinv,
                                                         int* __restrict__ csr, int N, int NB) {
    __shared__ int cnt[BKT_NODES];
    __shared__ int sd[256];
    int b = blockIdx.x, t = threadIdx.x;
    int node0 = b * BKT_NODES;
    int nn = min(BKT_NODES, N - node0);
    int ebase = blockoff[b];
    int ecnt = blockoff[b + 1] - ebase;
    cnt[t] = 0; cnt[t + 256] = 0;
    __syncthreads();
    for (int i = t; i < ecnt; i += 256)
        atomicAdd(&cnt[ebuf[ebase + i] >> 20], 1);
    __syncthreads();
    int c0 = cnt[2 * t], c1 = cnt[2 * t + 1];
    sd[t] = c0 + c1;
    __syncthreads();
#pragma unroll
    for (int o = 1; o < 256; o <<= 1) {
        int u = (t >= o) ? sd[t - o] : 0;
        __syncthreads();
        sd[t] += u;
        __syncthreads();
    }
    int ex = sd[t] - c0 - c1;                       // exclusive prefix for node 2t
    if (2 * t < nn) {
        rowptr[node0 + 2 * t] = ebase + ex;
        dinv[node0 + 2 * t]   = rsqrtf((float)c0 + 1.0f);
    }
    if (2 * t + 1 < nn) {
        rowptr[node0 + 2 * t + 1] = ebase + ex + c0;
        dinv[node0 + 2 * t + 1]   = rsqrtf((float)c1 + 1.0f);
    }
    if (b == NB - 1 && t == 0) rowptr[N] = ebase + ecnt;   // = E
    __syncthreads();            // all cnt reads done
    cnt[2 * t] = ex;            // reuse cnt as scatter cursor
    cnt[2 * t + 1] = ex + c0;
    __syncthreads();
    for (int i = t; i < ecnt; i += 256) {
        int rec = ebuf[ebase + i];
        int p = atomicAdd(&cnt[rec >> 20], 1);
        csr[ebase + p] = rec & 0xFFFFF;
    }
}

// ---------------- W transpose + hi/lo bf16 split ----------------

__global__ __launch_bounds__(256) void wsplit_kernel(const float* __restrict__ W2,
                                                     const float* __restrict__ W3,
                                                     unsigned short* __restrict__ WT) {
    int t = blockIdx.x * blockDim.x + threadIdx.x;   // 0 .. 32767
    int which = t >> 14;
    int idx = t & 16383;
    int k = idx >> 7, c = idx & 127;
    const float* W = which ? W3 : W2;
    float w = W[k * 128 + c];
    unsigned short hi = f2bf(w);
    unsigned short lo = f2bf(w - bf2f(hi));
    unsigned short* Th = WT + (size_t)which * 2 * 16384;
    unsigned short* Tl = Th + 16384;
    Th[c * 128 + k] = hi;
    Tl[c * 128 + k] = lo;
}

// W1T tables: [hi/lo][col=128][k=32], k>=26 zero-padded.
__global__ __launch_bounds__(256) void wsplit1_kernel(const float* __restrict__ W1,
                                                      unsigned short* __restrict__ W1T) {
    int t = blockIdx.x * blockDim.x + threadIdx.x;   // 0 .. 4095
    int c = t >> 5, k = t & 31;
    float w = (k < 26) ? W1[k * 128 + c] : 0.f;
    unsigned short hi = f2bf(w);
    unsigned short lo = f2bf(w - bf2f(hi));
    W1T[c * 32 + k]        = hi;
    W1T[4096 + c * 32 + k] = lo;
}

// ---------------- x pad: xp[N][32] fp32, k>=26 zeroed ----------------

__global__ __launch_bounds__(256) void xpad_kernel(const float* __restrict__ x,
                                                   float* __restrict__ xp, int N) {
    int t = blockIdx.x * blockDim.x + threadIdx.x;
    if (t >= N * 32) return;
    int i = t >> 5, k = t & 31;
    xp[t] = (k < 26) ? x[(size_t)i * 26 + k] : 0.f;
}

// ---------------- layer 1 aggregate: 8 rows/iter, 16B/lane ----------------

__global__ __launch_bounds__(256) void aggx8_kernel(const float* __restrict__ xp,
                                                    const float* __restrict__ dinv,
                                                    const int* __restrict__ rowptr,
                                                    const int* __restrict__ csr,
                                                    float* __restrict__ yp, int N) {
    int wid  = (int)((blockIdx.x * blockDim.x + threadIdx.x) >> 6);
    int lane = threadIdx.x & 63;
    if (wid >= N) return;
    const int i = wid;
    int start = __builtin_amdgcn_readfirstlane(rowptr[i]);
    int end   = __builtin_amdgcn_readfirstlane(rowptr[i + 1]);
    int grp = lane >> 3;        // 0..7 : edge slot
    int fl  = lane & 7;         // features fl*4 .. fl*4+3

    float4 acc = make_float4(0.f, 0.f, 0.f, 0.f);
    int e = start;
    for (; e + 8 <= end; e += 8) {
        int ci = csr[e + grp];
        float dv = dinv[ci];
        float4 v = *(const float4*)(xp + (size_t)ci * 32 + fl * 4);
        acc.x = fmaf(dv, v.x, acc.x); acc.y = fmaf(dv, v.y, acc.y);
        acc.z = fmaf(dv, v.z, acc.z); acc.w = fmaf(dv, v.w, acc.w);
    }
    if (e < end) {
        int e0 = e + grp;
        if (e0 < end) {
            int ci = csr[e0];
            float dv = dinv[ci];
            float4 v = *(const float4*)(xp + (size_t)ci * 32 + fl * 4);
            acc.x = fmaf(dv, v.x, acc.x); acc.y = fmaf(dv, v.y, acc.y);
            acc.z = fmaf(dv, v.z, acc.z); acc.w = fmaf(dv, v.w, acc.w);
        }
    }
#pragma unroll
    for (int off = 8; off <= 32; off <<= 1) {
        acc.x += __shfl_xor(acc.x, off);
        acc.y += __shfl_xor(acc.y, off);
        acc.z += __shfl_xor(acc.z, off);
        acc.w += __shfl_xor(acc.w, off);
    }
    float di = dinv[i];
    float4 xv = *(const float4*)(xp + (size_t)i * 32 + fl * 4);
    acc.x = fmaf(di, xv.x, acc.x); acc.y = fmaf(di, xv.y, acc.y);
    acc.z = fmaf(di, xv.z, acc.z); acc.w = fmaf(di, xv.w, acc.w);
    if (grp == 0) {
        float4 o = make_float4(acc.x * di, acc.y * di, acc.z * di, acc.w * di);
        *(float4*)(yp + (size_t)i * 32 + fl * 4) = o;
    }
}

// ---------------- layer-1 MFMA matmul: h = relu(yp @ W1 + b1), K=32 ----------

__global__ __launch_bounds__(256) void mm1_mfma_kernel(const float* __restrict__ yp,
                                                       const unsigned short* __restrict__ W1T,
                                                       const float* __restrict__ b1,
                                                       float* __restrict__ h, int N) {
    int wave = threadIdx.x >> 6;
    int lane = threadIdx.x & 63;
    int r0 = blockIdx.x * 64 + wave * 16;
    int arow = r0 + (lane & 15);
    int acl = min(arow, N - 1);
    int kgrp = lane >> 4;
    const float* yrow = yp + (size_t)acl * 32 + kgrp * 8;

    float4 v0 = ((const float4*)yrow)[0];
    float4 v1 = ((const float4*)yrow)[1];
    float va[8] = {v0.x, v0.y, v0.z, v0.w, v1.x, v1.y, v1.z, v1.w};
    BF8 ah, al;
#pragma unroll
    for (int j = 0; j < 8; ++j) {
        unsigned short hb = f2bf(va[j]);
        ah.u[j] = hb;
        al.u[j] = f2bf(va[j] - bf2f(hb));
    }

    const unsigned short* bh_base = W1T + (size_t)(lane & 15) * 32 + kgrp * 8;
    const unsigned short* bl_base = bh_base + 4096;

    f32x4 acc[8];
#pragma unroll
    for (int i = 0; i < 8; ++i) acc[i] = f32x4{0.f, 0.f, 0.f, 0.f};

#pragma unroll
    for (int ct = 0; ct < 8; ++ct) {
        BF8 bh, bl;
        bh.v = *(const bf16x8*)(bh_base + (size_t)ct * 16 * 32);
        bl.v = *(const bf16x8*)(bl_base + (size_t)ct * 16 * 32);
        acc[ct] = __builtin_amdgcn_mfma_f32_16x16x32_bf16(ah.v, bh.v, acc[ct], 0, 0, 0);
        acc[ct] = __builtin_amdgcn_mfma_f32_16x16x32_bf16(al.v, bh.v, acc[ct], 0, 0, 0);
        acc[ct] = __builtin_amdgcn_mfma_f32_16x16x32_bf16(ah.v, bl.v, acc[ct], 0, 0, 0);
    }

    int rbase = r0 + (lane >> 4) * 4;
#pragma unroll
    for (int r = 0; r < 4; ++r) {
        int row = rbase + r;
        if (row < N) {
#pragma unroll
            for (int ct = 0; ct < 8; ++ct) {
                int col = ct * 16 + (lane & 15);
                h[(size_t)row * 128 + col] = fmaxf(acc[ct][r] + b1[col], 0.f);
            }
        }
    }
}

// ------- MFMA matmul with LDS-staged B: s = dinv * (h @ W), 2-phase K-split --
// lB[tab][c][k_local], 16B chunks stored at (chunk ^ (c&7)) for uniform banks.

__global__ __launch_bounds__(256) void mm_mfma_kernel(const float* __restrict__ h,
                                                      const unsigned short* __restrict__ WTh,
                                                      const unsigned short* __restrict__ WTl,
                                                      const float* __restrict__ dinv,
                                                      unsigned short* __restrict__ s, int N) {
    __shared__ unsigned short lB[2][8192];          // 2 tables x 128 c x 64 k = 32 KB
    int tid  = threadIdx.x;
    int wave = tid >> 6;
    int lane = tid & 63;
    int r0 = blockIdx.x * 64 + wave * 16;
    int arow = r0 + (lane & 15);
    int acl = min(arow, N - 1);
    int kgrp = lane >> 4;                           // 0..3
    const float* hrow = h + (size_t)acl * 128 + kgrp * 8;

    f32x4 acc[8];
#pragma unroll
    for (int i = 0; i < 8; ++i) acc[i] = f32x4{0.f, 0.f, 0.f, 0.f};

    int c_frag = lane & 15;                         // column fragment base (within 16)

#pragma unroll
    for (int phase = 0; phase < 2; ++phase) {
        // cooperative stage: 2 tables x 128 cols x 8 chunks(16B) = 2048 chunks
        for (int u = tid; u < 2048; u += 256) {
            int tab = u >> 10;
            int rem = u & 1023;
            int c   = rem >> 3;
            int c16 = rem & 7;
            const unsigned short* srcp = (tab ? WTl : WTh) + c * 128 + phase * 64 + c16 * 8;
            *(uint4*)&lB[tab][c * 64 + ((c16 ^ (c & 7)) << 3)] = *(const uint4*)srcp;
        }
        __syncthreads();

#pragma unroll
        for (int ks2 = 0; ks2 < 2; ++ks2) {
            const float4* p = (const float4*)(hrow + phase * 64 + ks2 * 32);
            float4 v0 = p[0], v1 = p[1];
            float va[8] = {v0.x, v0.y, v0.z, v0.w, v1.x, v1.y, v1.z, v1.w};
            BF8 ah, al;
#pragma unroll
            for (int j = 0; j < 8; ++j) {
                unsigned short hb = f2bf(va[j]);
                ah.u[j] = hb;
                al.u[j] = f2bf(va[j] - bf2f(hb));
            }
#pragma unroll
            for (int ct = 0; ct < 8; ++ct) {
                int c = ct * 16 + c_frag;
                int chunk = (ks2 * 4 + kgrp) ^ (c & 7);
                BF8 bh, bl;
                bh.v = *(const bf16x8*)&lB[0][c * 64 + (chunk << 3)];
                bl.v = *(const bf16x8*)&lB[1][c * 64 + (chunk << 3)];
                acc[ct] = __builtin_amdgcn_mfma_f32_16x16x32_bf16(ah.v, bh.v, acc[ct], 0, 0, 0);
                acc[ct] = __builtin_amdgcn_mfma_f32_16x16x32_bf16(al.v, bh.v, acc[ct], 0, 0, 0);
                acc[ct] = __builtin_amdgcn_mfma_f32_16x16x32_bf16(ah.v, bl.v, acc[ct], 0, 0, 0);
            }
        }
        __syncthreads();        // protect lB before next-phase overwrite
    }

    // C/D layout: col=lane&15, row=(lane>>4)*4+reg
    int rbase = r0 + (lane >> 4) * 4;
#pragma unroll
    for (int r = 0; r < 4; ++r) {
        int row = rbase + r;
        if (row < N) {
            float di = dinv[row];
#pragma unroll
            for (int ct = 0; ct < 8; ++ct) {
                int col = ct * 16 + c_frag;
                s[(size_t)row * 128 + col] = f2bf(acc[ct][r] * di);
            }
        }
    }
}

// ------------- aggregation: 4 rows/iter, 16B/lane, butterfly reduce ---------

template <int RELU>
__global__ __launch_bounds__(256) void aggregate4_kernel(const unsigned short* __restrict__ s,
                                                         const float* __restrict__ dinv,
                                                         const int* __restrict__ rowptr,
                                                         const int* __restrict__ csr,
                                                         const float* __restrict__ bias,
                                                         float* __restrict__ hout, int N) {
    int wid  = (int)((blockIdx.x * blockDim.x + threadIdx.x) >> 6);
    int lane = threadIdx.x & 63;
    if (wid >= N) return;
    const int i = wid;
    int start = __builtin_amdgcn_readfirstlane(rowptr[i]);
    int end   = __builtin_amdgcn_readfirstlane(rowptr[i + 1]);
    int grp = lane >> 4;        // 0..3 : edge slot
    int fl  = lane & 15;        // features fl*8 .. fl*8+7

    float acc[8];
#pragma unroll
    for (int j = 0; j < 8; ++j) acc[j] = 0.f;

    int e = start;
    for (; e + 8 <= end; e += 8) {
        int ci0 = csr[e + grp];
        int ci1 = csr[e + 4 + grp];
        uint4 w0 = *(const uint4*)(s + (size_t)ci0 * 128 + fl * 8);
        uint4 w1 = *(const uint4*)(s + (size_t)ci1 * 128 + fl * 8);
        acc[0] += bflo(w0.x); acc[1] += bfhi(w0.x);
        acc[2] += bflo(w0.y); acc[3] += bfhi(w0.y);
        acc[4] += bflo(w0.z); acc[5] += bfhi(w0.z);
        acc[6] += bflo(w0.w); acc[7] += bfhi(w0.w);
        acc[0] += bflo(w1.x); acc[1] += bfhi(w1.x);
        acc[2] += bflo(w1.y); acc[3] += bfhi(w1.y);
        acc[4] += bflo(w1.z); acc[5] += bfhi(w1.z);
        acc[6] += bflo(w1.w); acc[7] += bfhi(w1.w);
    }
    if (e < end) {
        int e0 = e + grp, e1 = e + 4 + grp;
        if (e0 < end) {
            int ci = csr[e0];
            uint4 w = *(const uint4*)(s + (size_t)ci * 128 + fl * 8);
            acc[0] += bflo(w.x); acc[1] += bfhi(w.x);
            acc[2] += bflo(w.y); acc[3] += bfhi(w.y);
            acc[4] += bflo(w.z); acc[5] += bfhi(w.z);
            acc[6] += bflo(w.w); acc[7] += bfhi(w.w);
        }
        if (e1 < end) {
            int ci = csr[e1];
            uint4 w = *(const uint4*)(s + (size_t)ci * 128 + fl * 8);
            acc[0] += bflo(w.x); acc[1] += bfhi(w.x);
            acc[2] += bflo(w.y); acc[3] += bfhi(w.y);
            acc[4] += bflo(w.z); acc[5] += bfhi(w.z);
            acc[6] += bflo(w.w); acc[7] += bfhi(w.w);
        }
    }
#pragma unroll
    for (int off = 16; off <= 32; off <<= 1) {
#pragma unroll
        for (int j = 0; j < 8; ++j) acc[j] += __shfl_xor(acc[j], off);
    }
    // self-loop term
    {
        uint4 w = *(const uint4*)(s + (size_t)i * 128 + fl * 8);
        acc[0] += bflo(w.x); acc[1] += bfhi(w.x);
        acc[2] += bflo(w.y); acc[3] += bfhi(w.y);
        acc[4] += bflo(w.z); acc[5] += bfhi(w.z);
        acc[6] += bflo(w.w); acc[7] += bfhi(w.w);
    }
    float di = dinv[i];
    int j0 = grp * 2;
    int f = fl * 8 + j0;
    const float2 bv = ((const float2*)bias)[f >> 1];
    float ox = acc[j0] * di + bv.x;
    float oy = acc[j0 + 1] * di + bv.y;
    if (RELU) { ox = fmaxf(ox, 0.f); oy = fmaxf(oy, 0.f); }
    ((float2*)hout)[(size_t)i * 64 + (f >> 1)] = make_float2(ox, oy);
}

// ---------------- mean pool (fp32 h) ----------------

__global__ __launch_bounds__(128) void pool_kernel(const float* __restrict__ h,
                                                   const int* __restrict__ batch,
                                                   float* __restrict__ out, int N) {
    int g = blockIdx.x;
    int j = threadIdx.x;
    int lo = 0, hi = N;
    while (lo < hi) { int mid = (lo + hi) >> 1; if (batch[mid] < g) lo = mid + 1; else hi = mid; }
    int start = lo;
    hi = N;
    while (lo < hi) { int mid = (lo + hi) >> 1; if (batch[mid] < g + 1) lo = mid + 1; else hi = mid; }
    int end = lo;
    float acc = 0.f;
    for (int i = start; i < end; ++i) acc += h[(size_t)i * 128 + j];
    int cnt = end - start;
    out[(size_t)g * 128 + j] = acc / (float)max(cnt, 1);
}

// ---------------- driver ----------------

extern "C" void kernel_launch(void* const* d_in, const int* in_sizes, int n_in,
                              void* d_out, int out_size, void* d_ws, size_t ws_size,
                              hipStream_t stream) {
    const float* x     = (const float*)d_in[0];
    const int*   edge  = (const int*)d_in[1];
    const int*   batch = (const int*)d_in[2];
    const float* W1    = (const float*)d_in[3];
    const float* b1    = (const float*)d_in[4];
    const float* W2    = (const float*)d_in[5];
    const float* b2    = (const float*)d_in[6];
    const float* W3    = (const float*)d_in[7];
    const float* b3    = (const float*)d_in[8];
    float* out = (float*)d_out;

    const int N = in_sizes[2];
    const int E = in_sizes[1] / 2;
    const int G = out_size / 128;

    const int* src = edge;
    const int* dst = edge + E;

    char* base = (char*)d_ws;
    size_t off = 0;
    auto carve = [&](size_t bytes) -> char* {
        char* p = base + off;
        off = (off + bytes + 255) & ~(size_t)255;
        return p;
    };
    int*            rowptr     = (int*)carve((size_t)(N + 1) * 4);
    float*          dinv       = (float*)carve((size_t)N * 4);
    int*            csr        = (int*)carve((size_t)E * 4);
    int*            ebuf       = (int*)carve((size_t)E * 4);
    unsigned short* WT         = (unsigned short*)carve((size_t)4 * 16384 * 2);
    unsigned short* W1T        = (unsigned short*)carve((size_t)2 * 4096 * 2);
    int*            bcount     = (int*)carve(256 * 4);
    int*            blockoff   = (int*)carve(260 * 4);
    int*            bucket_cur = (int*)carve(256 * 4);
    float*          xp         = (float*)carve((size_t)N * 32 * 4);
    float*          yp         = (float*)carve((size_t)N * 32 * 4);
    float*          bufH       = (float*)carve((size_t)N * 128 * 4);
    unsigned short* bufS       = (unsigned short*)carve((size_t)N * 128 * 2);

    if (off > ws_size) {
        hipMemsetAsync(d_out, 0, (size_t)out_size * 4, stream);
        return;
    }

    const int NB   = (N + BKT_NODES - 1) / BKT_NODES;   // 196 (must be <= 256)
    const int EBK  = (E + EPB - 1) / EPB;               // 196

    hipMemsetAsync(bcount, 0, 256 * 4, stream);
    bucket_hist_kernel<<<EBK, 256, 0, stream>>>(dst, bcount, E);
    scan_buckets_kernel<<<1, 256, 0, stream>>>(bcount, blockoff, bucket_cur, NB);
    bucket_scatter_kernel<<<EBK, 256, 0, stream>>>(src, dst, bucket_cur, ebuf, E);
    bucket_csr_kernel<<<NB, 256, 0, stream>>>(ebuf, blockoff, rowptr, dinv, csr, N, NB);
    wsplit_kernel<<<128, 256, 0, stream>>>(W2, W3, WT);
    wsplit1_kernel<<<16, 256, 0, stream>>>(W1, W1T);
    xpad_kernel<<<(N * 32 + 255) / 256, 256, 0, stream>>>(x, xp, N);

    const unsigned short* WT2h = WT;
    const unsigned short* WT2l = WT + 16384;
    const unsigned short* WT3h = WT + 2 * 16384;
    const unsigned short* WT3l = WT + 3 * 16384;

    int mfbk = (N + 63) / 64;
    int agbk = (N + 3) / 4;

    // layer 1: aggregate in padded x-space, then h1 = relu(y@W1 + b1) via MFMA
    aggx8_kernel<<<agbk, 256, 0, stream>>>(xp, dinv, rowptr, csr, yp, N);
    mm1_mfma_kernel<<<mfbk, 256, 0, stream>>>(yp, W1T, b1, bufH, N);
    // layer 2
    mm_mfma_kernel<<<mfbk, 256, 0, stream>>>(bufH, WT2h, WT2l, dinv, bufS, N);
    aggregate4_kernel<1><<<agbk, 256, 0, stream>>>(bufS, dinv, rowptr, csr, b2, bufH, N);
    // layer 3
    mm_mfma_kernel<<<mfbk, 256, 0, stream>>>(bufH, WT3h, WT3l, dinv, bufS, N);
    aggregate4_kernel<0><<<agbk, 256, 0, stream>>>(bufS, dinv, rowptr, csr, b3, bufH, N);
    // pool
    pool_kernel<<<G, 128, 0, stream>>>(bufH, batch, out, N);
}

// Round 18
// 423.751 us; speedup vs baseline: 4.0641x; 1.0064x over previous
//
#include <hip/hip_runtime.h>
#include <hip/hip_bf16.h>

// GCN: 3x (h = relu( dinv .* Agg( dinv .* (h@W) ) + b)) then mean-pool by graph.
// CSR build: bucketed counting sort. Layer 1: bf16 x-table [N][32], 16-row/iter
// gather, MFMA matmul K=32. Layers 2/3: MFMA hi/lo split with LDS-staged B;
// aggregate 16 edges in flight (round-12: test latency-bound vs fabric ceiling).
// Round-17 fix: ACC_W macro param collided with .w member (w.w -> w0.w0);
// replaced with inline function.

typedef __attribute__((ext_vector_type(8))) __bf16 bf16x8;
typedef __attribute__((ext_vector_type(4))) float f32x4;

union BF8 { bf16x8 v; unsigned short u[8]; };

#define BKT_SHIFT 9
#define BKT_NODES 512
#define EPB 8192               // edges per block in bucket passes

__device__ inline unsigned short f2bf(float f) {
    union { float f; unsigned u; } x; x.f = f;
    unsigned r = (x.u + 0x7FFFu + ((x.u >> 16) & 1u)) >> 16;
    return (unsigned short)r;
}
__device__ inline float bf2f(unsigned short u) {
    union { float f; unsigned u; } x; x.u = ((unsigned)u) << 16;
    return x.f;
}
__device__ inline float bflo(unsigned v) {
    union { float f; unsigned u; } x; x.u = (v & 0xFFFFu) << 16; return x.f;
}
__device__ inline float bfhi(unsigned v) {
    union { float f; unsigned u; } x; x.u = v & 0xFFFF0000u; return x.f;
}
__device__ inline void accw(float acc[8], uint4 v) {
    acc[0] += bflo(v.x); acc[1] += bfhi(v.x);
    acc[2] += bflo(v.y); acc[3] += bfhi(v.y);
    acc[4] += bflo(v.z); acc[5] += bfhi(v.z);
    acc[6] += bflo(v.w); acc[7] += bfhi(v.w);
}

// ---------------- CSR build: bucketed counting sort ----------------

__global__ __launch_bounds__(256) void bucket_hist_kernel(const int* __restrict__ dst,
                                                          int* __restrict__ bcount, int E) {
    __shared__ int lh[256];
    int t = threadIdx.x;
    lh[t] = 0;
    __syncthreads();
    int base = blockIdx.x * EPB;
    for (int i = t; i < EPB; i += 256) {
        int e = base + i;
        if (e < E) atomicAdd(&lh[dst[e] >> BKT_SHIFT], 1);
    }
    __syncthreads();
    if (lh[t]) atomicAdd(&bcount[t], lh[t]);
}

__global__ __launch_bounds__(256) void scan_buckets_kernel(const int* __restrict__ bcount,
                                                           int* __restrict__ blockoff,
                                                           int* __restrict__ bucket_cur, int NB) {
    __shared__ int sd[256];
    int t = threadIdx.x;
    int v = (t < NB) ? bcount[t] : 0;
    sd[t] = v;
    __syncthreads();
#pragma unroll
    for (int o = 1; o < 256; o <<= 1) {
        int u = (t >= o) ? sd[t - o] : 0;
        __syncthreads();
        sd[t] += u;
        __syncthreads();
    }
    if (t < NB) { int ex = sd[t] - v; blockoff[t] = ex; bucket_cur[t] = ex; }
    if (t == 255) blockoff[NB] = sd[255];   // = E
}

// scatter edges into bucket-grouped ebuf; rec = src | ((dst&511)<<20)
__global__ __launch_bounds__(256) void bucket_scatter_kernel(const int* __restrict__ src,
                                                             const int* __restrict__ dst,
                                                             int* __restrict__ bucket_cur,
                                                             int* __restrict__ ebuf, int E) {
    __shared__ int lh[256];
    __shared__ int lb[256];
    int t = threadIdx.x;
    lh[t] = 0;
    __syncthreads();
    int base = blockIdx.x * EPB;
    for (int i = t; i < EPB; i += 256) {
        int e = base + i;
        if (e < E) atomicAdd(&lh[dst[e] >> BKT_SHIFT], 1);
    }
    __syncthreads();
    int n = lh[t];
    if (n) lb[t] = atomicAdd(&bucket_cur[t], n);
    lh[t] = 0;
    __syncthreads();
    for (int i = t; i < EPB; i += 256) {
        int e = base + i;
        if (e < E) {
            int d = dst[e];
            int k = d >> BKT_SHIFT;
            int r = atomicAdd(&lh[k], 1);
            ebuf[lb[k] + r] = src[e] | ((d & (BKT_NODES - 1)) << 20);
        }
    }
}

// per-bucket CSR finalize: node counts, rowptr, dinv, sorted csr (src ids)
__global__ __launch_bounds__(256) void bucket_csr_kernel(const int* __restrict__ ebuf,
                                                         const int* __restrict__ blockoff,
                                                         int* __restrict__ rowptr,
                                                         float* __restrict__ dinv,
                                                         int* __restrict__ csr, int N, int NB) {
    __shared__ int cnt[BKT_NODES];
    __shared__ int sd[256];
    int b = blockIdx.x, t = threadIdx.x;
    int node0 = b * BKT_NODES;
    int nn = min(BKT_NODES, N - node0);
    int ebase = blockoff[b];
    int ecnt = blockoff[b + 1] - ebase;
    cnt[t] = 0; cnt[t + 256] = 0;
    __syncthreads();
    for (int i = t; i < ecnt; i += 256)
        atomicAdd(&cnt[ebuf[ebase + i] >> 20], 1);
    __syncthreads();
    int c0 = cnt[2 * t], c1 = cnt[2 * t + 1];
    sd[t] = c0 + c1;
    __syncthreads();
#pragma unroll
    for (int o = 1; o < 256; o <<= 1) {
        int u = (t >= o) ? sd[t - o] : 0;
        __syncthreads();
        sd[t] += u;
        __syncthreads();
    }
    int ex = sd[t] - c0 - c1;                       // exclusive prefix for node 2t
    if (2 * t < nn) {
        rowptr[node0 + 2 * t] = ebase + ex;
        dinv[node0 + 2 * t]   = rsqrtf((float)c0 + 1.0f);
    }
    if (2 * t + 1 < nn) {
        rowptr[node0 + 2 * t + 1] = ebase + ex + c0;
        dinv[node0 + 2 * t + 1]   = rsqrtf((float)c1 + 1.0f);
    }
    if (b == NB - 1 && t == 0) rowptr[N] = ebase + ecnt;   // = E
    __syncthreads();            // all cnt reads done
    cnt[2 * t] = ex;            // reuse cnt as scatter cursor
    cnt[2 * t + 1] = ex + c0;
    __syncthreads();
    for (int i = t; i < ecnt; i += 256) {
        int rec = ebuf[ebase + i];
        int p = atomicAdd(&cnt[rec >> 20], 1);
        csr[ebase + p] = rec & 0xFFFFF;
    }
}

// ---------------- W transpose + hi/lo bf16 split ----------------

__global__ __launch_bounds__(256) void wsplit_kernel(const float* __restrict__ W2,
                                                     const float* __restrict__ W3,
                                                     unsigned short* __restrict__ WT) {
    int t = blockIdx.x * blockDim.x + threadIdx.x;   // 0 .. 32767
    int which = t >> 14;
    int idx = t & 16383;
    int k = idx >> 7, c = idx & 127;
    const float* W = which ? W3 : W2;
    float w = W[k * 128 + c];
    unsigned short hi = f2bf(w);
    unsigned short lo = f2bf(w - bf2f(hi));
    unsigned short* Th = WT + (size_t)which * 2 * 16384;
    unsigned short* Tl = Th + 16384;
    Th[c * 128 + k] = hi;
    Tl[c * 128 + k] = lo;
}

// W1T tables: [hi/lo][col=128][k=32], k>=26 zero-padded.
__global__ __launch_bounds__(256) void wsplit1_kernel(const float* __restrict__ W1,
                                                      unsigned short* __restrict__ W1T) {
    int t = blockIdx.x * blockDim.x + threadIdx.x;   // 0 .. 4095
    int c = t >> 5, k = t & 31;
    float w = (k < 26) ? W1[k * 128 + c] : 0.f;
    unsigned short hi = f2bf(w);
    unsigned short lo = f2bf(w - bf2f(hi));
    W1T[c * 32 + k]        = hi;
    W1T[4096 + c * 32 + k] = lo;
}

// ---------------- x pad: xs[N][32] bf16, k>=26 zeroed ----------------

__global__ __launch_bounds__(256) void xpad_kernel(const float* __restrict__ x,
                                                   unsigned short* __restrict__ xs, int N) {
    int t = blockIdx.x * blockDim.x + threadIdx.x;
    if (t >= N * 32) return;
    int i = t >> 5, k = t & 31;
    xs[t] = (k < 26) ? f2bf(x[(size_t)i * 26 + k]) : (unsigned short)0;
}

// ------------- layer 1 aggregate: 16 rows/iter, 16B/lane, bf16 table --------
// yp[i] = dinv[i] * ( dinv[i]*x[i] + sum_{src->i} dinv[src]*x[src] ), fp32 out

__global__ __launch_bounds__(256) void aggx16_kernel(const unsigned short* __restrict__ xs,
                                                     const float* __restrict__ dinv,
                                                     const int* __restrict__ rowptr,
                                                     const int* __restrict__ csr,
                                                     float* __restrict__ yp, int N) {
    int wid  = (int)((blockIdx.x * blockDim.x + threadIdx.x) >> 6);
    int lane = threadIdx.x & 63;
    if (wid >= N) return;
    const int i = wid;
    int start = __builtin_amdgcn_readfirstlane(rowptr[i]);
    int end   = __builtin_amdgcn_readfirstlane(rowptr[i + 1]);
    int grp = lane >> 2;        // 0..15 : edge slot
    int fl  = lane & 3;         // features fl*8 .. fl*8+7 (8 bf16 = 16B)

    float acc[8];
#pragma unroll
    for (int j = 0; j < 8; ++j) acc[j] = 0.f;

    int e = start;
    for (; e + 16 <= end; e += 16) {
        int ci = csr[e + grp];
        float dv = dinv[ci];
        uint4 v = *(const uint4*)(xs + (size_t)ci * 32 + fl * 8);
        acc[0] = fmaf(dv, bflo(v.x), acc[0]); acc[1] = fmaf(dv, bfhi(v.x), acc[1]);
        acc[2] = fmaf(dv, bflo(v.y), acc[2]); acc[3] = fmaf(dv, bfhi(v.y), acc[3]);
        acc[4] = fmaf(dv, bflo(v.z), acc[4]); acc[5] = fmaf(dv, bfhi(v.z), acc[5]);
        acc[6] = fmaf(dv, bflo(v.w), acc[6]); acc[7] = fmaf(dv, bfhi(v.w), acc[7]);
    }
    if (e < end) {
        int e0 = e + grp;
        if (e0 < end) {
            int ci = csr[e0];
            float dv = dinv[ci];
            uint4 v = *(const uint4*)(xs + (size_t)ci * 32 + fl * 8);
            acc[0] = fmaf(dv, bflo(v.x), acc[0]); acc[1] = fmaf(dv, bfhi(v.x), acc[1]);
            acc[2] = fmaf(dv, bflo(v.y), acc[2]); acc[3] = fmaf(dv, bfhi(v.y), acc[3]);
            acc[4] = fmaf(dv, bflo(v.z), acc[4]); acc[5] = fmaf(dv, bfhi(v.z), acc[5]);
            acc[6] = fmaf(dv, bflo(v.w), acc[6]); acc[7] = fmaf(dv, bfhi(v.w), acc[7]);
        }
    }
    // reduce across the 16 edge-slot groups (lane bits 2..5)
#pragma unroll
    for (int off = 4; off <= 32; off <<= 1) {
#pragma unroll
        for (int j = 0; j < 8; ++j) acc[j] += __shfl_xor(acc[j], off);
    }
    // self-loop term + final dinv scale
    float di = dinv[i];
    uint4 v = *(const uint4*)(xs + (size_t)i * 32 + fl * 8);
    acc[0] = fmaf(di, bflo(v.x), acc[0]); acc[1] = fmaf(di, bfhi(v.x), acc[1]);
    acc[2] = fmaf(di, bflo(v.y), acc[2]); acc[3] = fmaf(di, bfhi(v.y), acc[3]);
    acc[4] = fmaf(di, bflo(v.z), acc[4]); acc[5] = fmaf(di, bfhi(v.z), acc[5]);
    acc[6] = fmaf(di, bflo(v.w), acc[6]); acc[7] = fmaf(di, bfhi(v.w), acc[7]);
    if (grp == 0) {
        float4 o0 = make_float4(acc[0] * di, acc[1] * di, acc[2] * di, acc[3] * di);
        float4 o1 = make_float4(acc[4] * di, acc[5] * di, acc[6] * di, acc[7] * di);
        *(float4*)(yp + (size_t)i * 32 + fl * 8)     = o0;
        *(float4*)(yp + (size_t)i * 32 + fl * 8 + 4) = o1;
    }
}

// ---------------- layer-1 MFMA matmul: h = relu(yp @ W1 + b1), K=32 ----------

__global__ __launch_bounds__(256) void mm1_mfma_kernel(const float* __restrict__ yp,
                                                       const unsigned short* __restrict__ W1T,
                                                       const float* __restrict__ b1,
                                                       float* __restrict__ h, int N) {
    int wave = threadIdx.x >> 6;
    int lane = threadIdx.x & 63;
    int r0 = blockIdx.x * 64 + wave * 16;
    int arow = r0 + (lane & 15);
    int acl = min(arow, N - 1);
    int kgrp = lane >> 4;
    const float* yrow = yp + (size_t)acl * 32 + kgrp * 8;

    float4 v0 = ((const float4*)yrow)[0];
    float4 v1 = ((const float4*)yrow)[1];
    float va[8] = {v0.x, v0.y, v0.z, v0.w, v1.x, v1.y, v1.z, v1.w};
    BF8 ah, al;
#pragma unroll
    for (int j = 0; j < 8; ++j) {
        unsigned short hb = f2bf(va[j]);
        ah.u[j] = hb;
        al.u[j] = f2bf(va[j] - bf2f(hb));
    }

    const unsigned short* bh_base = W1T + (size_t)(lane & 15) * 32 + kgrp * 8;
    const unsigned short* bl_base = bh_base + 4096;

    f32x4 acc[8];
#pragma unroll
    for (int i = 0; i < 8; ++i) acc[i] = f32x4{0.f, 0.f, 0.f, 0.f};

#pragma unroll
    for (int ct = 0; ct < 8; ++ct) {
        BF8 bh, bl;
        bh.v = *(const bf16x8*)(bh_base + (size_t)ct * 16 * 32);
        bl.v = *(const bf16x8*)(bl_base + (size_t)ct * 16 * 32);
        acc[ct] = __builtin_amdgcn_mfma_f32_16x16x32_bf16(ah.v, bh.v, acc[ct], 0, 0, 0);
        acc[ct] = __builtin_amdgcn_mfma_f32_16x16x32_bf16(al.v, bh.v, acc[ct], 0, 0, 0);
        acc[ct] = __builtin_amdgcn_mfma_f32_16x16x32_bf16(ah.v, bl.v, acc[ct], 0, 0, 0);
    }

    int rbase = r0 + (lane >> 4) * 4;
#pragma unroll
    for (int r = 0; r < 4; ++r) {
        int row = rbase + r;
        if (row < N) {
#pragma unroll
            for (int ct = 0; ct < 8; ++ct) {
                int col = ct * 16 + (lane & 15);
                h[(size_t)row * 128 + col] = fmaxf(acc[ct][r] + b1[col], 0.f);
            }
        }
    }
}

// ------- MFMA matmul with LDS-staged B: s = dinv * (h @ W), 2-phase K-split --

__global__ __launch_bounds__(256) void mm_mfma_kernel(const float* __restrict__ h,
                                                      const unsigned short* __restrict__ WTh,
                                                      const unsigned short* __restrict__ WTl,
                                                      const float* __restrict__ dinv,
                                                      unsigned short* __restrict__ s, int N) {
    __shared__ unsigned short lB[2][8192];          // 2 tables x 128 c x 64 k = 32 KB
    int tid  = threadIdx.x;
    int wave = tid >> 6;
    int lane = tid & 63;
    int r0 = blockIdx.x * 64 + wave * 16;
    int arow = r0 + (lane & 15);
    int acl = min(arow, N - 1);
    int kgrp = lane >> 4;                           // 0..3
    const float* hrow = h + (size_t)acl * 128 + kgrp * 8;

    f32x4 acc[8];
#pragma unroll
    for (int i = 0; i < 8; ++i) acc[i] = f32x4{0.f, 0.f, 0.f, 0.f};

    int c_frag = lane & 15;

#pragma unroll
    for (int phase = 0; phase < 2; ++phase) {
        for (int u = tid; u < 2048; u += 256) {
            int tab = u >> 10;
            int rem = u & 1023;
            int c   = rem >> 3;
            int c16 = rem & 7;
            const unsigned short* srcp = (tab ? WTl : WTh) + c * 128 + phase * 64 + c16 * 8;
            *(uint4*)&lB[tab][c * 64 + ((c16 ^ (c & 7)) << 3)] = *(const uint4*)srcp;
        }
        __syncthreads();

#pragma unroll
        for (int ks2 = 0; ks2 < 2; ++ks2) {
            const float4* p = (const float4*)(hrow + phase * 64 + ks2 * 32);
            float4 v0 = p[0], v1 = p[1];
            float va[8] = {v0.x, v0.y, v0.z, v0.w, v1.x, v1.y, v1.z, v1.w};
            BF8 ah, al;
#pragma unroll
            for (int j = 0; j < 8; ++j) {
                unsigned short hb = f2bf(va[j]);
                ah.u[j] = hb;
                al.u[j] = f2bf(va[j] - bf2f(hb));
            }
#pragma unroll
            for (int ct = 0; ct < 8; ++ct) {
                int c = ct * 16 + c_frag;
                int chunk = (ks2 * 4 + kgrp) ^ (c & 7);
                BF8 bh, bl;
                bh.v = *(const bf16x8*)&lB[0][c * 64 + (chunk << 3)];
                bl.v = *(const bf16x8*)&lB[1][c * 64 + (chunk << 3)];
                acc[ct] = __builtin_amdgcn_mfma_f32_16x16x32_bf16(ah.v, bh.v, acc[ct], 0, 0, 0);
                acc[ct] = __builtin_amdgcn_mfma_f32_16x16x32_bf16(al.v, bh.v, acc[ct], 0, 0, 0);
                acc[ct] = __builtin_amdgcn_mfma_f32_16x16x32_bf16(ah.v, bl.v, acc[ct], 0, 0, 0);
            }
        }
        __syncthreads();
    }

    int rbase = r0 + (lane >> 4) * 4;
#pragma unroll
    for (int r = 0; r < 4; ++r) {
        int row = rbase + r;
        if (row < N) {
            float di = dinv[row];
#pragma unroll
            for (int ct = 0; ct < 8; ++ct) {
                int col = ct * 16 + c_frag;
                s[(size_t)row * 128 + col] = f2bf(acc[ct][r] * di);
            }
        }
    }
}

// ------- aggregation: 16 edges in flight, 16B/lane, butterfly reduce --------

template <int RELU>
__global__ __launch_bounds__(256) void aggregate4_kernel(const unsigned short* __restrict__ s,
                                                         const float* __restrict__ dinv,
                                                         const int* __restrict__ rowptr,
                                                         const int* __restrict__ csr,
                                                         const float* __restrict__ bias,
                                                         float* __restrict__ hout, int N) {
    int wid  = (int)((blockIdx.x * blockDim.x + threadIdx.x) >> 6);
    int lane = threadIdx.x & 63;
    if (wid >= N) return;
    const int i = wid;
    int start = __builtin_amdgcn_readfirstlane(rowptr[i]);
    int end   = __builtin_amdgcn_readfirstlane(rowptr[i + 1]);
    int grp = lane >> 4;        // 0..3 : edge slot
    int fl  = lane & 15;        // features fl*8 .. fl*8+7

    float acc[8];
#pragma unroll
    for (int j = 0; j < 8; ++j) acc[j] = 0.f;

    int e = start;
    for (; e + 16 <= end; e += 16) {
        int ci0 = csr[e + grp];
        int ci1 = csr[e + 4 + grp];
        int ci2 = csr[e + 8 + grp];
        int ci3 = csr[e + 12 + grp];
        uint4 w0 = *(const uint4*)(s + (size_t)ci0 * 128 + fl * 8);
        uint4 w1 = *(const uint4*)(s + (size_t)ci1 * 128 + fl * 8);
        uint4 w2 = *(const uint4*)(s + (size_t)ci2 * 128 + fl * 8);
        uint4 w3 = *(const uint4*)(s + (size_t)ci3 * 128 + fl * 8);
        accw(acc, w0); accw(acc, w1); accw(acc, w2); accw(acc, w3);
    }
    for (; e + 4 <= end; e += 4) {
        int ci = csr[e + grp];
        uint4 w0 = *(const uint4*)(s + (size_t)ci * 128 + fl * 8);
        accw(acc, w0);
    }
    if (e < end) {
        int e0 = e + grp;
        if (e0 < end) {
            int ci = csr[e0];
            uint4 w0 = *(const uint4*)(s + (size_t)ci * 128 + fl * 8);
            accw(acc, w0);
        }
    }
    // reduce across the 4 edge-slot groups
#pragma unroll
    for (int off = 16; off <= 32; off <<= 1) {
#pragma unroll
        for (int j = 0; j < 8; ++j) acc[j] += __shfl_xor(acc[j], off);
    }
    // self-loop term
    {
        uint4 w0 = *(const uint4*)(s + (size_t)i * 128 + fl * 8);
        accw(acc, w0);
    }
    float di = dinv[i];
    int j0 = grp * 2;
    int f = fl * 8 + j0;
    const float2 bv = ((const float2*)bias)[f >> 1];
    float ox = acc[j0] * di + bv.x;
    float oy = acc[j0 + 1] * di + bv.y;
    if (RELU) { ox = fmaxf(ox, 0.f); oy = fmaxf(oy, 0.f); }
    ((float2*)hout)[(size_t)i * 64 + (f >> 1)] = make_float2(ox, oy);
}

// ---------------- mean pool (fp32 h) ----------------

__global__ __launch_bounds__(128) void pool_kernel(const float* __restrict__ h,
                                                   const int* __restrict__ batch,
                                                   float* __restrict__ out, int N) {
    int g = blockIdx.x;
    int j = threadIdx.x;
    int lo = 0, hi = N;
    while (lo < hi) { int mid = (lo + hi) >> 1; if (batch[mid] < g) lo = mid + 1; else hi = mid; }
    int start = lo;
    hi = N;
    while (lo < hi) { int mid = (lo + hi) >> 1; if (batch[mid] < g + 1) lo = mid + 1; else hi = mid; }
    int end = lo;
    float acc = 0.f;
    for (int i = start; i < end; ++i) acc += h[(size_t)i * 128 + j];
    int cnt = end - start;
    out[(size_t)g * 128 + j] = acc / (float)max(cnt, 1);
}

// ---------------- driver ----------------

extern "C" void kernel_launch(void* const* d_in, const int* in_sizes, int n_in,
                              void* d_out, int out_size, void* d_ws, size_t ws_size,
                              hipStream_t stream) {
    const float* x     = (const float*)d_in[0];
    const int*   edge  = (const int*)d_in[1];
    const int*   batch = (const int*)d_in[2];
    const float* W1    = (const float*)d_in[3];
    const float* b1    = (const float*)d_in[4];
    const float* W2    = (const float*)d_in[5];
    const float* b2    = (const float*)d_in[6];
    const float* W3    = (const float*)d_in[7];
    const float* b3    = (const float*)d_in[8];
    float* out = (float*)d_out;

    const int N = in_sizes[2];
    const int E = in_sizes[1] / 2;
    const int G = out_size / 128;

    const int* src = edge;
    const int* dst = edge + E;

    char* base = (char*)d_ws;
    size_t off = 0;
    auto carve = [&](size_t bytes) -> char* {
        char* p = base + off;
        off = (off + bytes + 255) & ~(size_t)255;
        return p;
    };
    int*            rowptr     = (int*)carve((size_t)(N + 1) * 4);
    float*          dinv       = (float*)carve((size_t)N * 4);
    int*            csr        = (int*)carve((size_t)E * 4);
    int*            ebuf       = (int*)carve((size_t)E * 4);
    unsigned short* WT         = (unsigned short*)carve((size_t)4 * 16384 * 2);
    unsigned short* W1T        = (unsigned short*)carve((size_t)2 * 4096 * 2);
    int*            bcount     = (int*)carve(256 * 4);
    int*            blockoff   = (int*)carve(260 * 4);
    int*            bucket_cur = (int*)carve(256 * 4);
    unsigned short* xs         = (unsigned short*)carve((size_t)N * 32 * 2);
    float*          yp         = (float*)carve((size_t)N * 32 * 4);
    float*          bufH       = (float*)carve((size_t)N * 128 * 4);
    unsigned short* bufS       = (unsigned short*)carve((size_t)N * 128 * 2);

    if (off > ws_size) {
        hipMemsetAsync(d_out, 0, (size_t)out_size * 4, stream);
        return;
    }

    const int NB   = (N + BKT_NODES - 1) / BKT_NODES;   // 196 (must be <= 256)
    const int EBK  = (E + EPB - 1) / EPB;               // 196

    hipMemsetAsync(bcount, 0, 256 * 4, stream);
    bucket_hist_kernel<<<EBK, 256, 0, stream>>>(dst, bcount, E);
    scan_buckets_kernel<<<1, 256, 0, stream>>>(bcount, blockoff, bucket_cur, NB);
    bucket_scatter_kernel<<<EBK, 256, 0, stream>>>(src, dst, bucket_cur, ebuf, E);
    bucket_csr_kernel<<<NB, 256, 0, stream>>>(ebuf, blockoff, rowptr, dinv, csr, N, NB);
    wsplit_kernel<<<128, 256, 0, stream>>>(W2, W3, WT);
    wsplit1_kernel<<<16, 256, 0, stream>>>(W1, W1T);
    xpad_kernel<<<(N * 32 + 255) / 256, 256, 0, stream>>>(x, xs, N);

    const unsigned short* WT2h = WT;
    const unsigned short* WT2l = WT + 16384;
    const unsigned short* WT3h = WT + 2 * 16384;
    const unsigned short* WT3l = WT + 3 * 16384;

    int mfbk = (N + 63) / 64;
    int agbk = (N + 3) / 4;

    // layer 1: aggregate in bf16 x-space, then h1 = relu(y@W1 + b1) via MFMA
    aggx16_kernel<<<agbk, 256, 0, stream>>>(xs, dinv, rowptr, csr, yp, N);
    mm1_mfma_kernel<<<mfbk, 256, 0, stream>>>(yp, W1T, b1, bufH, N);
    // layer 2
    mm_mfma_kernel<<<mfbk, 256, 0, stream>>>(bufH, WT2h, WT2l, dinv, bufS, N);
    aggregate4_kernel<1><<<agbk, 256, 0, stream>>>(bufS, dinv, rowptr, csr, b2, bufH, N);
    // layer 3
    mm_mfma_kernel<<<mfbk, 256, 0, stream>>>(bufH, WT3h, WT3l, dinv, bufS, N);
    aggregate4_kernel<0><<<agbk, 256, 0, stream>>>(bufS, dinv, rowptr, csr, b3, bufH, N);
    // pool
    pool_kernel<<<G, 128, 0, stream>>>(bufH, batch, out, N);
}